// Round 3
// baseline (3130.508 us; speedup 1.0000x reference)
//
#include <hip/hip_runtime.h>
#include <hip/hip_bf16.h>
#include <math.h>

#define N0 100000
#define E0 600000
#define KP1 80000
#define KP2 64000
#define KP3 51200
#define F 128
#define RB 128

// ---------- helpers ----------
__device__ __forceinline__ unsigned fkey(float f) {
    unsigned u = __float_as_uint(f);
    return u ^ ((u & 0x80000000u) ? 0xFFFFFFFFu : 0x80000000u);
}

// ---------- aggregation: agg[dst] += x[src] ----------
__global__ __launch_bounds__(256) void aggK(const float* __restrict__ x,
                                            const int* __restrict__ src,
                                            const int* __restrict__ dst,
                                            float* __restrict__ agg, int nEdges) {
    int t = blockIdx.x * 256 + threadIdx.x;
    int e = t >> 5, q = t & 31;
    if (e >= nEdges) return;
    int s = src[e];
    if (s < 0) return;
    int d = dst[e];
    const float4 v = *(const float4*)(x + (size_t)s * F + q * 4);
    float* a = agg + (size_t)d * F + q * 4;
    unsafeAtomicAdd(a + 0, v.x);
    unsafeAtomicAdd(a + 1, v.y);
    unsafeAtomicAdd(a + 2, v.z);
    unsafeAtomicAdd(a + 3, v.w);
}

// ---------- fused conv: out = relu(agg@Wr.T + x@Wroot.T + br) ----------
#define BM 128
#define BKC 16
__global__ __launch_bounds__(256) void convK(const float* __restrict__ agg,
                                             const float* __restrict__ x,
                                             const float* __restrict__ Wr,
                                             const float* __restrict__ Wroot,
                                             const float* __restrict__ br,
                                             float* __restrict__ out, int n) {
    __shared__ float As[BKC][BM + 1];
    __shared__ float Ws[BKC][BM + 1];
    int tid = threadIdx.x;
    int bm = blockIdx.x * BM;
    int rg = tid >> 4, cg = tid & 15;   // 16 row-groups x 16 col-groups
    int lr = tid >> 2, kq = tid & 3;    // load mapping
    float acc[8][8];
#pragma unroll
    for (int i = 0; i < 8; i++)
#pragma unroll
        for (int j = 0; j < 8; j++) acc[i][j] = 0.f;

    for (int ph = 0; ph < 2; ph++) {
        const float* A = ph ? x : agg;
        const float* W = ph ? Wroot : Wr;
        for (int kk = 0; kk < F; kk += BKC) {
#pragma unroll
            for (int h = 0; h < 2; h++) {
                int ar = lr + h * 64;  // 0..127
                float4 v = make_float4(0.f, 0.f, 0.f, 0.f);
                if (bm + ar < n) v = *(const float4*)(A + (size_t)(bm + ar) * F + kk + kq * 4);
                As[kq * 4 + 0][ar] = v.x; As[kq * 4 + 1][ar] = v.y;
                As[kq * 4 + 2][ar] = v.z; As[kq * 4 + 3][ar] = v.w;
                float4 wv = *(const float4*)(W + (size_t)ar * F + kk + kq * 4);
                Ws[kq * 4 + 0][ar] = wv.x; Ws[kq * 4 + 1][ar] = wv.y;
                Ws[kq * 4 + 2][ar] = wv.z; Ws[kq * 4 + 3][ar] = wv.w;
            }
            __syncthreads();
#pragma unroll
            for (int k = 0; k < BKC; k++) {
                float a[8], w[8];
#pragma unroll
                for (int i = 0; i < 8; i++) a[i] = As[k][rg + 16 * i];
#pragma unroll
                for (int j = 0; j < 8; j++) w[j] = Ws[k][cg + 16 * j];
#pragma unroll
                for (int i = 0; i < 8; i++)
#pragma unroll
                    for (int j = 0; j < 8; j++) acc[i][j] = fmaf(a[i], w[j], acc[i][j]);
            }
            __syncthreads();
        }
    }
#pragma unroll
    for (int i = 0; i < 8; i++) {
        int row = bm + rg + 16 * i;
        if (row < n) {
#pragma unroll
            for (int j = 0; j < 8; j++) {
                int col = cg + 16 * j;
                out[(size_t)row * F + col] = fmaxf(acc[i][j] + br[col], 0.f);
            }
        }
    }
}

// ---------- score: tanh((h.pw)/||pw||), plus sortable key ----------
__global__ __launch_bounds__(256) void scoreK(const float* __restrict__ h,
                                              const float* __restrict__ pw,
                                              float* __restrict__ sc,
                                              unsigned* __restrict__ keys, int n) {
    int wv = threadIdx.x >> 6, lane = threadIdx.x & 63;
    int row = blockIdx.x * 4 + wv;
    if (row >= n) return;
    float p0 = pw[lane], p1 = pw[lane + 64];
    float h0 = h[(size_t)row * F + lane], h1 = h[(size_t)row * F + lane + 64];
    float d = h0 * p0 + h1 * p1;
    float q = p0 * p0 + p1 * p1;
    for (int off = 32; off; off >>= 1) {
        d += __shfl_down(d, off);
        q += __shfl_down(q, off);
    }
    if (lane == 0) {
        float s = tanhf(d / sqrtf(q));
        sc[row] = s;
        keys[row] = fkey(s);
    }
}

// ---------- radix select (k-th largest) ----------
__global__ void initSelK(unsigned* hist, unsigned* st, int k) {
    hist[threadIdx.x] = 0;
    if (threadIdx.x == 0) { st[0] = 0u; st[1] = (unsigned)k; }
}

__global__ __launch_bounds__(256) void histK(const unsigned* __restrict__ keys, int n,
                                             int p, const unsigned* __restrict__ st,
                                             unsigned* __restrict__ hist) {
    __shared__ unsigned lh[256];
    lh[threadIdx.x] = 0;
    __syncthreads();
    unsigned prefix = st[0];
    int i = blockIdx.x * 256 + threadIdx.x;
    if (i < n) {
        unsigned key = keys[i];
        bool m = (p == 0) || ((key >> (32 - 8 * p)) == (prefix >> (32 - 8 * p)));
        if (m) atomicAdd(&lh[(key >> (24 - 8 * p)) & 255u], 1u);
    }
    __syncthreads();
    if (lh[threadIdx.x]) atomicAdd(&hist[threadIdx.x], lh[threadIdx.x]);
}

__global__ void selectK(unsigned* hist, unsigned* st, int p) {
    __shared__ unsigned h[256];
    h[threadIdx.x] = hist[threadIdx.x];
    __syncthreads();
    if (threadIdx.x == 0) {
        unsigned krem = st[1], cum = 0;
        for (int b = 255; b >= 0; b--) {
            unsigned c = h[b];
            if (cum + c >= krem) {
                st[0] |= ((unsigned)b) << (24 - 8 * p);
                st[1] = krem - cum;
                break;
            }
            cum += c;
        }
    }
    __syncthreads();
    hist[threadIdx.x] = 0;
}

// ---------- exact ordered selection (new_idx assignment) ----------
__global__ __launch_bounds__(256) void countsK(const unsigned* __restrict__ keys, int n,
                                               const unsigned* __restrict__ st,
                                               int* __restrict__ bGT, int* __restrict__ bEQ) {
    __shared__ int cg_, ce_;
    if (threadIdx.x == 0) { cg_ = 0; ce_ = 0; }
    __syncthreads();
    unsigned t = st[0];
    int g = 0, e = 0;
    for (int it = 0; it < 4; it++) {
        int i = blockIdx.x * 1024 + it * 256 + threadIdx.x;
        if (i < n) {
            unsigned k = keys[i];
            g += (k > t);
            e += (k == t);
        }
    }
    atomicAdd(&cg_, g);
    atomicAdd(&ce_, e);
    __syncthreads();
    if (threadIdx.x == 0) { bGT[blockIdx.x] = cg_; bEQ[blockIdx.x] = ce_; }
}

__global__ void scanK(const int* bGT, const int* bEQ, int* sGT, int* sEQ, int nb) {
    if (threadIdx.x == 0 && blockIdx.x == 0) {
        int g = 0, e = 0;
        for (int b = 0; b < nb; b++) {
            sGT[b] = g; sEQ[b] = e;
            g += bGT[b]; e += bEQ[b];
        }
    }
}

__global__ __launch_bounds__(256) void markK(const unsigned* __restrict__ keys, int n,
                                             const unsigned* __restrict__ st,
                                             const int* __restrict__ sGT,
                                             const int* __restrict__ sEQ,
                                             int* __restrict__ nidx) {
    __shared__ int wG[4], wE[4];
    __shared__ int runG, runE;
    int tid = threadIdx.x, wv = tid >> 6, lane = tid & 63;
    if (tid == 0) { runG = 0; runE = 0; }
    unsigned t = st[0];
    int needEq = (int)st[1];
    int gOff = sGT[blockIdx.x], eOff = sEQ[blockIdx.x];
    unsigned long long mlt = (((unsigned long long)1) << lane) - 1ull;
    __syncthreads();
    for (int it = 0; it < 4; it++) {
        int i = blockIdx.x * 1024 + it * 256 + tid;
        bool inb = i < n;
        unsigned k = inb ? keys[i] : 0u;
        bool pG = inb && (k > t), pE = inb && (k == t);
        unsigned long long bG = __ballot(pG), bE = __ballot(pE);
        int lpG = __popcll(bG & mlt), lpE = __popcll(bE & mlt);
        if (lane == 0) { wG[wv] = __popcll(bG); wE[wv] = __popcll(bE); }
        __syncthreads();
        int woG = 0, woE = 0;
        for (int w = 0; w < wv; w++) { woG += wG[w]; woE += wE[w]; }
        int gB = gOff + runG + woG + lpG;
        int eB = eOff + runE + woE + lpE;
        int ni = -1;
        if (pG) ni = gB + (eB < needEq ? eB : needEq);
        else if (pE && eB < needEq) ni = gB + eB;
        if (inb) nidx[i] = ni;
        __syncthreads();
        if (tid == 0) {
            runG += wG[0] + wG[1] + wG[2] + wG[3];
            runE += wE[0] + wE[1] + wE[2] + wE[3];
        }
        __syncthreads();
    }
}

// ---------- gather+scale kept nodes ----------
__global__ __launch_bounds__(256) void gatherK(const float* __restrict__ h,
                                               const float* __restrict__ sc,
                                               const int* __restrict__ nidx,
                                               float* __restrict__ out, int n) {
    int t = blockIdx.x * 256 + threadIdx.x;
    int i = t >> 5, q = t & 31;
    if (i >= n) return;
    int ni = nidx[i];
    if (ni < 0) return;
    float s = sc[i];
    float4 v = *(const float4*)(h + (size_t)i * F + q * 4);
    v.x *= s; v.y *= s; v.z *= s; v.w *= s;
    *(float4*)(out + (size_t)ni * F + q * 4) = v;
}

// ---------- remap edges ----------
__global__ __launch_bounds__(256) void remapK(const int* __restrict__ srcIn,
                                              const int* __restrict__ dstIn,
                                              const int* __restrict__ nidx,
                                              int* __restrict__ srcOut,
                                              int* __restrict__ dstOut) {
    int e = blockIdx.x * 256 + threadIdx.x;
    if (e >= E0) return;
    int s = srcIn[e];
    int ns = -1, nd = 0;
    if (s >= 0) {
        ns = nidx[s];
        nd = nidx[dstIn[e]];
        if (ns < 0 || nd < 0) { ns = -1; nd = 0; }
    }
    srcOut[e] = ns;
    dstOut[e] = nd;
}

// ---------- readout: r[0:128]+=max, r[128:256]+=mean ----------
__global__ __launch_bounds__(128) void rpartK(const float* __restrict__ x, int k,
                                              float* __restrict__ pmax, float* __restrict__ psum) {
    int f = threadIdx.x;
    float m = -INFINITY, s = 0.f;
    for (int row = blockIdx.x; row < k; row += gridDim.x) {
        float v = x[(size_t)row * F + f];
        m = fmaxf(m, v);
        s += v;
    }
    pmax[blockIdx.x * F + f] = m;
    psum[blockIdx.x * F + f] = s;
}

__global__ __launch_bounds__(128) void rfinalK(const float* __restrict__ pmax,
                                               const float* __restrict__ psum, int k,
                                               float* __restrict__ r) {
    int f = threadIdx.x;
    float m = -INFINITY, s = 0.f;
    for (int b = 0; b < RB; b++) {
        m = fmaxf(m, pmax[b * F + f]);
        s += psum[b * F + f];
    }
    r[f] += m;
    r[F + f] += s / (float)k;
}

// ---------- final MLP ----------
__global__ __launch_bounds__(256) void mlpK(const float* __restrict__ r,
                                            const float* __restrict__ W1, const float* __restrict__ b1,
                                            const float* __restrict__ W2, const float* __restrict__ b2,
                                            const float* __restrict__ W3, const float* __restrict__ b3,
                                            float* __restrict__ out) {
    __shared__ float z0[256], z1[128], z2[64];
    int t = threadIdx.x;
    z0[t] = r[t];
    __syncthreads();
    if (t < 128) {
        float a = b1[t];
        for (int kk = 0; kk < 256; kk++) a = fmaf(W1[t * 256 + kk], z0[kk], a);
        z1[t] = fmaxf(a, 0.f);
    }
    __syncthreads();
    if (t < 64) {
        float a = b2[t];
        for (int kk = 0; kk < 128; kk++) a = fmaf(W2[t * 128 + kk], z1[kk], a);
        z2[t] = fmaxf(a, 0.f);
    }
    __syncthreads();
    if (t < 2) {
        float a = b3[t];
        for (int kk = 0; kk < 64; kk++) a = fmaf(W3[t * 64 + kk], z2[kk], a);
        out[t] = a;
    }
}

extern "C" void kernel_launch(void* const* d_in, const int* in_sizes, int n_in,
                              void* d_out, int out_size, void* d_ws, size_t ws_size,
                              hipStream_t stream) {
    const float* x = (const float*)d_in[0];
    const int* ei = (const int*)d_in[1];
    const float* Wr[3]    = { (const float*)d_in[2],  (const float*)d_in[6],  (const float*)d_in[10] };
    const float* br[3]    = { (const float*)d_in[3],  (const float*)d_in[7],  (const float*)d_in[11] };
    const float* Wroot[3] = { (const float*)d_in[4],  (const float*)d_in[8],  (const float*)d_in[12] };
    const float* pw[3]    = { (const float*)d_in[5],  (const float*)d_in[9],  (const float*)d_in[13] };
    const float* W1 = (const float*)d_in[14];
    const float* b1 = (const float*)d_in[15];
    const float* W2 = (const float*)d_in[16];
    const float* b2 = (const float*)d_in[17];
    const float* W3 = (const float*)d_in[18];
    const float* b3 = (const float*)d_in[19];
    float* out = (float*)d_out;
    char* w = (char*)d_ws;

    size_t o = 0;
    auto alc = [&](size_t bytes) { size_t r = o; o += (bytes + 255) & ~(size_t)255; return r; };
    float*    bufA = (float*)(w + alc((size_t)N0 * F * 4));
    float*    bufB = (float*)(w + alc((size_t)KP1 * F * 4));
    float*    agg  = (float*)(w + alc((size_t)N0 * F * 4));
    float*    sc   = (float*)(w + alc((size_t)N0 * 4));
    unsigned* keys = (unsigned*)(w + alc((size_t)N0 * 4));
    int*      nidx = (int*)(w + alc((size_t)N0 * 4));
    int*      srcA = (int*)(w + alc((size_t)E0 * 4));
    int*      dstA = (int*)(w + alc((size_t)E0 * 4));
    int*      srcB = (int*)(w + alc((size_t)E0 * 4));
    int*      dstB = (int*)(w + alc((size_t)E0 * 4));
    unsigned* hist = (unsigned*)(w + alc(256 * 4));
    unsigned* st   = (unsigned*)(w + alc(64));
    int*      bGT  = (int*)(w + alc(128 * 4));
    int*      bEQ  = (int*)(w + alc(128 * 4));
    int*      sGT  = (int*)(w + alc(128 * 4));
    int*      sEQ  = (int*)(w + alc(128 * 4));
    float*    r    = (float*)(w + alc(256 * 4));
    float*    pmax = (float*)(w + alc((size_t)RB * F * 4));
    float*    psum = (float*)(w + alc((size_t)RB * F * 4));
    if (o > ws_size) return;  // workspace too small; fail loudly via validation

    hipMemsetAsync(r, 0, 256 * 4, stream);

    // per-layer driver
    const int ns[3] = { N0, KP1, KP2 };
    const int ks[3] = { KP1, KP2, KP3 };

    for (int L = 0; L < 3; L++) {
        int n = ns[L], k = ks[L];
        const float* xin = (L == 0) ? x : bufB;
        const int* srcIn = (L == 0) ? ei : (L == 1 ? srcA : srcB);
        const int* dstIn = (L == 0) ? ei + E0 : (L == 1 ? dstA : dstB);
        int* srcOut = (L == 1) ? srcB : srcA;
        int* dstOut = (L == 1) ? dstB : dstA;

        hipMemsetAsync(agg, 0, (size_t)n * F * 4, stream);
        aggK<<<(E0 * 32 + 255) / 256, 256, 0, stream>>>(xin, srcIn, dstIn, agg, E0);
        convK<<<(n + BM - 1) / BM, 256, 0, stream>>>(agg, xin, Wr[L], Wroot[L], br[L], bufA, n);
        scoreK<<<(n + 3) / 4, 256, 0, stream>>>(bufA, pw[L], sc, keys, n);

        initSelK<<<1, 256, 0, stream>>>(hist, st, k);
        for (int p = 0; p < 4; p++) {
            histK<<<(n + 255) / 256, 256, 0, stream>>>(keys, n, p, st, hist);
            selectK<<<1, 256, 0, stream>>>(hist, st, p);
        }
        int nb = (n + 1023) / 1024;
        countsK<<<nb, 256, 0, stream>>>(keys, n, st, bGT, bEQ);
        scanK<<<1, 1, 0, stream>>>(bGT, bEQ, sGT, sEQ, nb);
        markK<<<nb, 256, 0, stream>>>(keys, n, st, sGT, sEQ, nidx);

        gatherK<<<(n * 32 + 255) / 256, 256, 0, stream>>>(bufA, sc, nidx, bufB, n);
        if (L < 2)
            remapK<<<(E0 + 255) / 256, 256, 0, stream>>>(srcIn, dstIn, nidx, srcOut, dstOut);

        rpartK<<<RB, 128, 0, stream>>>(bufB, k, pmax, psum);
        rfinalK<<<1, 128, 0, stream>>>(pmax, psum, k, r);
    }

    mlpK<<<1, 256, 0, stream>>>(r, W1, b1, W2, b2, W3, b3, out);
}

// Round 4
// 1282.540 us; speedup vs baseline: 2.4409x; 2.4409x over previous
//
#include <hip/hip_runtime.h>
#include <hip/hip_bf16.h>
#include <math.h>

#define N0 100000
#define E0 600000
#define KP1 80000
#define KP2 64000
#define KP3 51200
#define F 128
#define RB 128
#define SCAN_CHUNK 1024
#define NCHUNK ((N0 + SCAN_CHUNK - 1) / SCAN_CHUNK)

// ---------- helpers ----------
__device__ __forceinline__ unsigned fkey(float f) {
    unsigned u = __float_as_uint(f);
    return u ^ ((u & 0x80000000u) ? 0xFFFFFFFFu : 0x80000000u);
}

// ---------- CSR build (once per launch) ----------
__global__ __launch_bounds__(256) void histDstK(const int* __restrict__ dst, unsigned* __restrict__ cnt) {
    int e = blockIdx.x * 256 + threadIdx.x;
    if (e < E0) atomicAdd(&cnt[dst[e]], 1u);
}

__global__ __launch_bounds__(256) void scanReduceK(const unsigned* __restrict__ cnt,
                                                   unsigned* __restrict__ chunkSum, int nbins) {
    __shared__ unsigned sh[256];
    int base = blockIdx.x * SCAN_CHUNK + threadIdx.x * 4;
    unsigned s = 0;
#pragma unroll
    for (int i = 0; i < 4; i++) { int b = base + i; if (b < nbins) s += cnt[b]; }
    sh[threadIdx.x] = s;
    __syncthreads();
    for (int off = 128; off; off >>= 1) {
        if (threadIdx.x < off) sh[threadIdx.x] += sh[threadIdx.x + off];
        __syncthreads();
    }
    if (threadIdx.x == 0) chunkSum[blockIdx.x] = sh[0];
}

__global__ void scanChunksK(const unsigned* __restrict__ chunkSum, unsigned* __restrict__ chunkOff,
                            int nchunks, unsigned* __restrict__ totalOut) {
    if (threadIdx.x == 0) {
        unsigned run = 0;
        for (int i = 0; i < nchunks; i++) { chunkOff[i] = run; run += chunkSum[i]; }
        *totalOut = run;
    }
}

__global__ __launch_bounds__(256) void scanFinalK(const unsigned* __restrict__ cnt,
                                                  const unsigned* __restrict__ chunkOff,
                                                  unsigned* __restrict__ rowptr, int nbins) {
    __shared__ unsigned sh[256];
    int t = threadIdx.x;
    int base = blockIdx.x * SCAN_CHUNK + t * 4;
    unsigned c[4], s = 0;
#pragma unroll
    for (int i = 0; i < 4; i++) { int b = base + i; c[i] = (b < nbins) ? cnt[b] : 0u; s += c[i]; }
    sh[t] = s;
    __syncthreads();
    for (int off = 1; off < 256; off <<= 1) {
        unsigned v = (t >= off) ? sh[t - off] : 0u;
        __syncthreads();
        sh[t] += v;
        __syncthreads();
    }
    unsigned basep = chunkOff[blockIdx.x] + sh[t] - s;
#pragma unroll
    for (int i = 0; i < 4; i++) {
        int b = base + i;
        if (b < nbins) { rowptr[b] = basep; basep += c[i]; }
    }
}

__global__ __launch_bounds__(256) void scatterFillK(const int* __restrict__ src,
                                                    const int* __restrict__ dst,
                                                    const unsigned* __restrict__ rowptr,
                                                    unsigned* __restrict__ fill,
                                                    int* __restrict__ sortedSrc) {
    int e = blockIdx.x * 256 + threadIdx.x;
    if (e >= E0) return;
    int d = dst[e];
    unsigned p = rowptr[d] + atomicAdd(&fill[d], 1u);
    sortedSrc[p] = src[e];
}

__global__ __launch_bounds__(256) void iotaK(int* o, int n) {
    int i = blockIdx.x * 256 + threadIdx.x;
    if (i < n) o[i] = i;
}

// ---------- segmented aggregation: agg[j] = sum_{e in seg(orig[j])} x[src[e]] ----------
__global__ __launch_bounds__(256) void aggSegK(const float* __restrict__ x,
                                               const int* __restrict__ srcCur,
                                               const unsigned* __restrict__ rowptr,
                                               const int* __restrict__ orig,
                                               float* __restrict__ agg, int n) {
    int g = blockIdx.x * 8 + (threadIdx.x >> 5);
    int q = threadIdx.x & 31;
    if (g >= n) return;
    int d = orig[g];
    unsigned e0 = rowptr[d], e1 = rowptr[d + 1];
    float4 acc = make_float4(0.f, 0.f, 0.f, 0.f);
    for (unsigned e = e0; e < e1; e++) {
        int s = srcCur[e];
        if (s < 0) continue;
        float4 v = *(const float4*)(x + (size_t)s * F + q * 4);
        acc.x += v.x; acc.y += v.y; acc.z += v.z; acc.w += v.w;
    }
    *(float4*)(agg + (size_t)g * F + q * 4) = acc;
}

__global__ __launch_bounds__(256) void buildOrigK(const int* __restrict__ origIn,
                                                  const int* __restrict__ nidx,
                                                  int* __restrict__ origOut, int n) {
    int i = blockIdx.x * 256 + threadIdx.x;
    if (i < n) { int ni = nidx[i]; if (ni >= 0) origOut[ni] = origIn[i]; }
}

__global__ __launch_bounds__(256) void remapSrcK(const int* __restrict__ srcIn,
                                                 const int* __restrict__ nidx,
                                                 int* __restrict__ srcOut) {
    int e = blockIdx.x * 256 + threadIdx.x;
    if (e >= E0) return;
    int s = srcIn[e];
    srcOut[e] = (s >= 0) ? nidx[s] : -1;
}

// ---------- fused conv: out = relu(agg@Wr.T + x@Wroot.T + br) ----------
#define BM 128
#define BKC 16
__global__ __launch_bounds__(256) void convK(const float* __restrict__ agg,
                                             const float* __restrict__ x,
                                             const float* __restrict__ Wr,
                                             const float* __restrict__ Wroot,
                                             const float* __restrict__ br,
                                             float* __restrict__ out, int n) {
    __shared__ float As[BKC][BM + 1];
    __shared__ float Ws[BKC][BM + 1];
    int tid = threadIdx.x;
    int bm = blockIdx.x * BM;
    int rg = tid >> 4, cg = tid & 15;
    int lr = tid >> 2, kq = tid & 3;
    float acc[8][8];
#pragma unroll
    for (int i = 0; i < 8; i++)
#pragma unroll
        for (int j = 0; j < 8; j++) acc[i][j] = 0.f;

    for (int ph = 0; ph < 2; ph++) {
        const float* A = ph ? x : agg;
        const float* W = ph ? Wroot : Wr;
        for (int kk = 0; kk < F; kk += BKC) {
#pragma unroll
            for (int h = 0; h < 2; h++) {
                int ar = lr + h * 64;
                float4 v = make_float4(0.f, 0.f, 0.f, 0.f);
                if (bm + ar < n) v = *(const float4*)(A + (size_t)(bm + ar) * F + kk + kq * 4);
                As[kq * 4 + 0][ar] = v.x; As[kq * 4 + 1][ar] = v.y;
                As[kq * 4 + 2][ar] = v.z; As[kq * 4 + 3][ar] = v.w;
                float4 wv = *(const float4*)(W + (size_t)ar * F + kk + kq * 4);
                Ws[kq * 4 + 0][ar] = wv.x; Ws[kq * 4 + 1][ar] = wv.y;
                Ws[kq * 4 + 2][ar] = wv.z; Ws[kq * 4 + 3][ar] = wv.w;
            }
            __syncthreads();
#pragma unroll
            for (int k = 0; k < BKC; k++) {
                float a[8], w[8];
#pragma unroll
                for (int i = 0; i < 8; i++) a[i] = As[k][rg + 16 * i];
#pragma unroll
                for (int j = 0; j < 8; j++) w[j] = Ws[k][cg + 16 * j];
#pragma unroll
                for (int i = 0; i < 8; i++)
#pragma unroll
                    for (int j = 0; j < 8; j++) acc[i][j] = fmaf(a[i], w[j], acc[i][j]);
            }
            __syncthreads();
        }
    }
#pragma unroll
    for (int i = 0; i < 8; i++) {
        int row = bm + rg + 16 * i;
        if (row < n) {
#pragma unroll
            for (int j = 0; j < 8; j++) {
                int col = cg + 16 * j;
                out[(size_t)row * F + col] = fmaxf(acc[i][j] + br[col], 0.f);
            }
        }
    }
}

// ---------- score: tanh((h.pw)/||pw||), plus sortable key ----------
__global__ __launch_bounds__(256) void scoreK(const float* __restrict__ h,
                                              const float* __restrict__ pw,
                                              float* __restrict__ sc,
                                              unsigned* __restrict__ keys, int n) {
    int wv = threadIdx.x >> 6, lane = threadIdx.x & 63;
    int row = blockIdx.x * 4 + wv;
    if (row >= n) return;
    float p0 = pw[lane], p1 = pw[lane + 64];
    float h0 = h[(size_t)row * F + lane], h1 = h[(size_t)row * F + lane + 64];
    float d = h0 * p0 + h1 * p1;
    float q = p0 * p0 + p1 * p1;
    for (int off = 32; off; off >>= 1) {
        d += __shfl_down(d, off);
        q += __shfl_down(q, off);
    }
    if (lane == 0) {
        float s = tanhf(d / sqrtf(q));
        sc[row] = s;
        keys[row] = fkey(s);
    }
}

// ---------- radix select (k-th largest) ----------
__global__ void initSelK(unsigned* hist, unsigned* st, int k) {
    hist[threadIdx.x] = 0;
    if (threadIdx.x == 0) { st[0] = 0u; st[1] = (unsigned)k; }
}

__global__ __launch_bounds__(256) void histK(const unsigned* __restrict__ keys, int n,
                                             int p, const unsigned* __restrict__ st,
                                             unsigned* __restrict__ hist) {
    __shared__ unsigned lh[256];
    lh[threadIdx.x] = 0;
    __syncthreads();
    unsigned prefix = st[0];
    int i = blockIdx.x * 256 + threadIdx.x;
    if (i < n) {
        unsigned key = keys[i];
        bool m = (p == 0) || ((key >> (32 - 8 * p)) == (prefix >> (32 - 8 * p)));
        if (m) atomicAdd(&lh[(key >> (24 - 8 * p)) & 255u], 1u);
    }
    __syncthreads();
    if (lh[threadIdx.x]) atomicAdd(&hist[threadIdx.x], lh[threadIdx.x]);
}

__global__ void selectK(unsigned* hist, unsigned* st, int p) {
    __shared__ unsigned h[256];
    h[threadIdx.x] = hist[threadIdx.x];
    __syncthreads();
    if (threadIdx.x == 0) {
        unsigned krem = st[1], cum = 0;
        for (int b = 255; b >= 0; b--) {
            unsigned c = h[b];
            if (cum + c >= krem) {
                st[0] |= ((unsigned)b) << (24 - 8 * p);
                st[1] = krem - cum;
                break;
            }
            cum += c;
        }
    }
    __syncthreads();
    hist[threadIdx.x] = 0;
}

// ---------- exact ordered selection (new_idx assignment) ----------
__global__ __launch_bounds__(256) void countsK(const unsigned* __restrict__ keys, int n,
                                               const unsigned* __restrict__ st,
                                               int* __restrict__ bGT, int* __restrict__ bEQ) {
    __shared__ int cg_, ce_;
    if (threadIdx.x == 0) { cg_ = 0; ce_ = 0; }
    __syncthreads();
    unsigned t = st[0];
    int g = 0, e = 0;
    for (int it = 0; it < 4; it++) {
        int i = blockIdx.x * 1024 + it * 256 + threadIdx.x;
        if (i < n) {
            unsigned k = keys[i];
            g += (k > t);
            e += (k == t);
        }
    }
    atomicAdd(&cg_, g);
    atomicAdd(&ce_, e);
    __syncthreads();
    if (threadIdx.x == 0) { bGT[blockIdx.x] = cg_; bEQ[blockIdx.x] = ce_; }
}

__global__ void scanK(const int* bGT, const int* bEQ, int* sGT, int* sEQ, int nb) {
    if (threadIdx.x == 0 && blockIdx.x == 0) {
        int g = 0, e = 0;
        for (int b = 0; b < nb; b++) {
            sGT[b] = g; sEQ[b] = e;
            g += bGT[b]; e += bEQ[b];
        }
    }
}

__global__ __launch_bounds__(256) void markK(const unsigned* __restrict__ keys, int n,
                                             const unsigned* __restrict__ st,
                                             const int* __restrict__ sGT,
                                             const int* __restrict__ sEQ,
                                             int* __restrict__ nidx) {
    __shared__ int wG[4], wE[4];
    __shared__ int runG, runE;
    int tid = threadIdx.x, wv = tid >> 6, lane = tid & 63;
    if (tid == 0) { runG = 0; runE = 0; }
    unsigned t = st[0];
    int needEq = (int)st[1];
    int gOff = sGT[blockIdx.x], eOff = sEQ[blockIdx.x];
    unsigned long long mlt = (((unsigned long long)1) << lane) - 1ull;
    __syncthreads();
    for (int it = 0; it < 4; it++) {
        int i = blockIdx.x * 1024 + it * 256 + tid;
        bool inb = i < n;
        unsigned k = inb ? keys[i] : 0u;
        bool pG = inb && (k > t), pE = inb && (k == t);
        unsigned long long bG = __ballot(pG), bE = __ballot(pE);
        int lpG = __popcll(bG & mlt), lpE = __popcll(bE & mlt);
        if (lane == 0) { wG[wv] = __popcll(bG); wE[wv] = __popcll(bE); }
        __syncthreads();
        int woG = 0, woE = 0;
        for (int w = 0; w < wv; w++) { woG += wG[w]; woE += wE[w]; }
        int gB = gOff + runG + woG + lpG;
        int eB = eOff + runE + woE + lpE;
        int ni = -1;
        if (pG) ni = gB + (eB < needEq ? eB : needEq);
        else if (pE && eB < needEq) ni = gB + eB;
        if (inb) nidx[i] = ni;
        __syncthreads();
        if (tid == 0) {
            runG += wG[0] + wG[1] + wG[2] + wG[3];
            runE += wE[0] + wE[1] + wE[2] + wE[3];
        }
        __syncthreads();
    }
}

// ---------- gather+scale kept nodes ----------
__global__ __launch_bounds__(256) void gatherK(const float* __restrict__ h,
                                               const float* __restrict__ sc,
                                               const int* __restrict__ nidx,
                                               float* __restrict__ out, int n) {
    int t = blockIdx.x * 256 + threadIdx.x;
    int i = t >> 5, q = t & 31;
    if (i >= n) return;
    int ni = nidx[i];
    if (ni < 0) return;
    float s = sc[i];
    float4 v = *(const float4*)(h + (size_t)i * F + q * 4);
    v.x *= s; v.y *= s; v.z *= s; v.w *= s;
    *(float4*)(out + (size_t)ni * F + q * 4) = v;
}

// ---------- readout ----------
__global__ __launch_bounds__(128) void rpartK(const float* __restrict__ x, int k,
                                              float* __restrict__ pmax, float* __restrict__ psum) {
    int f = threadIdx.x;
    float m = -INFINITY, s = 0.f;
    for (int row = blockIdx.x; row < k; row += gridDim.x) {
        float v = x[(size_t)row * F + f];
        m = fmaxf(m, v);
        s += v;
    }
    pmax[blockIdx.x * F + f] = m;
    psum[blockIdx.x * F + f] = s;
}

__global__ __launch_bounds__(128) void rfinalK(const float* __restrict__ pmax,
                                               const float* __restrict__ psum, int k,
                                               float* __restrict__ r) {
    int f = threadIdx.x;
    float m = -INFINITY, s = 0.f;
    for (int b = 0; b < RB; b++) {
        m = fmaxf(m, pmax[b * F + f]);
        s += psum[b * F + f];
    }
    r[f] += m;
    r[F + f] += s / (float)k;
}

// ---------- final MLP ----------
__global__ __launch_bounds__(256) void mlpK(const float* __restrict__ r,
                                            const float* __restrict__ W1, const float* __restrict__ b1,
                                            const float* __restrict__ W2, const float* __restrict__ b2,
                                            const float* __restrict__ W3, const float* __restrict__ b3,
                                            float* __restrict__ out) {
    __shared__ float z0[256], z1[128], z2[64];
    int t = threadIdx.x;
    z0[t] = r[t];
    __syncthreads();
    if (t < 128) {
        float a = b1[t];
        for (int kk = 0; kk < 256; kk++) a = fmaf(W1[t * 256 + kk], z0[kk], a);
        z1[t] = fmaxf(a, 0.f);
    }
    __syncthreads();
    if (t < 64) {
        float a = b2[t];
        for (int kk = 0; kk < 128; kk++) a = fmaf(W2[t * 128 + kk], z1[kk], a);
        z2[t] = fmaxf(a, 0.f);
    }
    __syncthreads();
    if (t < 2) {
        float a = b3[t];
        for (int kk = 0; kk < 64; kk++) a = fmaf(W3[t * 64 + kk], z2[kk], a);
        out[t] = a;
    }
}

extern "C" void kernel_launch(void* const* d_in, const int* in_sizes, int n_in,
                              void* d_out, int out_size, void* d_ws, size_t ws_size,
                              hipStream_t stream) {
    const float* x = (const float*)d_in[0];
    const int* ei = (const int*)d_in[1];
    const float* Wr[3]    = { (const float*)d_in[2],  (const float*)d_in[6],  (const float*)d_in[10] };
    const float* br[3]    = { (const float*)d_in[3],  (const float*)d_in[7],  (const float*)d_in[11] };
    const float* Wroot[3] = { (const float*)d_in[4],  (const float*)d_in[8],  (const float*)d_in[12] };
    const float* pw[3]    = { (const float*)d_in[5],  (const float*)d_in[9],  (const float*)d_in[13] };
    const float* W1 = (const float*)d_in[14];
    const float* b1 = (const float*)d_in[15];
    const float* W2 = (const float*)d_in[16];
    const float* b2 = (const float*)d_in[17];
    const float* W3 = (const float*)d_in[18];
    const float* b3 = (const float*)d_in[19];
    float* out = (float*)d_out;
    char* w = (char*)d_ws;

    size_t o = 0;
    auto alc = [&](size_t bytes) { size_t r = o; o += (bytes + 255) & ~(size_t)255; return r; };
    float*    bufA   = (float*)(w + alc((size_t)N0 * F * 4));
    float*    bufB   = (float*)(w + alc((size_t)KP1 * F * 4));
    float*    agg    = (float*)(w + alc((size_t)N0 * F * 4));
    float*    sc     = (float*)(w + alc((size_t)N0 * 4));
    unsigned* keys   = (unsigned*)(w + alc((size_t)N0 * 4));
    int*      nidx   = (int*)(w + alc((size_t)N0 * 4));
    int*      sSrc0  = (int*)(w + alc((size_t)E0 * 4));
    int*      srcCA  = (int*)(w + alc((size_t)E0 * 4));
    int*      srcCB  = (int*)(w + alc((size_t)E0 * 4));
    unsigned* cnt    = (unsigned*)(w + alc((size_t)N0 * 4));
    unsigned* rowptr = (unsigned*)(w + alc((size_t)(N0 + 1) * 4));
    int*      origA  = (int*)(w + alc((size_t)N0 * 4));
    int*      origB  = (int*)(w + alc((size_t)N0 * 4));
    unsigned* chS    = (unsigned*)(w + alc(NCHUNK * 4));
    unsigned* chO    = (unsigned*)(w + alc(NCHUNK * 4));
    unsigned* hist   = (unsigned*)(w + alc(256 * 4));
    unsigned* st     = (unsigned*)(w + alc(64));
    int*      bGT    = (int*)(w + alc(128 * 4));
    int*      bEQ    = (int*)(w + alc(128 * 4));
    int*      sGT    = (int*)(w + alc(128 * 4));
    int*      sEQ    = (int*)(w + alc(128 * 4));
    float*    r      = (float*)(w + alc(256 * 4));
    float*    pmax   = (float*)(w + alc((size_t)RB * F * 4));
    float*    psum   = (float*)(w + alc((size_t)RB * F * 4));
    if (o > ws_size) return;

    const int* srcOrig = ei;
    const int* dstOrig = ei + E0;

    // ----- build dst-sorted CSR once (stays valid for all layers: nidx is monotone) -----
    hipMemsetAsync(cnt, 0, (size_t)N0 * 4, stream);
    histDstK<<<(E0 + 255) / 256, 256, 0, stream>>>(dstOrig, cnt);
    scanReduceK<<<NCHUNK, 256, 0, stream>>>(cnt, chS, N0);
    scanChunksK<<<1, 1, 0, stream>>>(chS, chO, NCHUNK, rowptr + N0);
    scanFinalK<<<NCHUNK, 256, 0, stream>>>(cnt, chO, rowptr, N0);
    hipMemsetAsync(cnt, 0, (size_t)N0 * 4, stream);
    scatterFillK<<<(E0 + 255) / 256, 256, 0, stream>>>(srcOrig, dstOrig, rowptr, cnt, sSrc0);
    iotaK<<<(N0 + 255) / 256, 256, 0, stream>>>(origA, N0);

    hipMemsetAsync(r, 0, 256 * 4, stream);

    const int ns[3] = { N0, KP1, KP2 };
    const int ks[3] = { KP1, KP2, KP3 };
    const int* srcCur[3] = { sSrc0, srcCA, srcCB };
    int* srcNext[3] = { srcCA, srcCB, nullptr };
    const int* origCur[3] = { origA, origB, origA };
    int* origNext[3] = { origB, origA, nullptr };

    for (int L = 0; L < 3; L++) {
        int n = ns[L], k = ks[L];
        const float* xin = (L == 0) ? x : bufB;

        aggSegK<<<(n + 7) / 8, 256, 0, stream>>>(xin, srcCur[L], rowptr, origCur[L], agg, n);
        convK<<<(n + BM - 1) / BM, 256, 0, stream>>>(agg, xin, Wr[L], Wroot[L], br[L], bufA, n);
        scoreK<<<(n + 3) / 4, 256, 0, stream>>>(bufA, pw[L], sc, keys, n);

        initSelK<<<1, 256, 0, stream>>>(hist, st, k);
        for (int p = 0; p < 4; p++) {
            histK<<<(n + 255) / 256, 256, 0, stream>>>(keys, n, p, st, hist);
            selectK<<<1, 256, 0, stream>>>(hist, st, p);
        }
        int nb = (n + 1023) / 1024;
        countsK<<<nb, 256, 0, stream>>>(keys, n, st, bGT, bEQ);
        scanK<<<1, 1, 0, stream>>>(bGT, bEQ, sGT, sEQ, nb);
        markK<<<nb, 256, 0, stream>>>(keys, n, st, sGT, sEQ, nidx);

        gatherK<<<(n * 32 + 255) / 256, 256, 0, stream>>>(bufA, sc, nidx, bufB, n);
        if (L < 2) {
            buildOrigK<<<(n + 255) / 256, 256, 0, stream>>>(origCur[L], nidx, origNext[L], n);
            remapSrcK<<<(E0 + 255) / 256, 256, 0, stream>>>(srcCur[L], nidx, srcNext[L]);
        }

        rpartK<<<RB, 128, 0, stream>>>(bufB, k, pmax, psum);
        rfinalK<<<1, 128, 0, stream>>>(pmax, psum, k, r);
    }

    mlpK<<<1, 256, 0, stream>>>(r, W1, b1, W2, b2, W3, b3, out);
}

// Round 5
// 932.213 us; speedup vs baseline: 3.3581x; 1.3758x over previous
//
#include <hip/hip_runtime.h>
#include <hip/hip_bf16.h>
#include <math.h>

#define N0 100000
#define E0 600000
#define KP1 80000
#define KP2 64000
#define KP3 51200
#define F 128
#define RPB 2048   // readout partial blocks (stage 1)
#define RMID 128   // stage-2 blocks; each reduces RPB/RMID partials
#define SCAN_CHUNK 1024
#define NCHUNK ((N0 + SCAN_CHUNK - 1) / SCAN_CHUNK)

// ---------- helpers ----------
__device__ __forceinline__ unsigned fkey(float f) {
    unsigned u = __float_as_uint(f);
    return u ^ ((u & 0x80000000u) ? 0xFFFFFFFFu : 0x80000000u);
}

// ---------- CSR build (once per launch) ----------
__global__ __launch_bounds__(256) void histDstK(const int* __restrict__ dst, unsigned* __restrict__ cnt) {
    int e = blockIdx.x * 256 + threadIdx.x;
    if (e < E0) atomicAdd(&cnt[dst[e]], 1u);
}

__global__ __launch_bounds__(256) void scanReduceK(const unsigned* __restrict__ cnt,
                                                   unsigned* __restrict__ chunkSum, int nbins) {
    __shared__ unsigned sh[256];
    int base = blockIdx.x * SCAN_CHUNK + threadIdx.x * 4;
    unsigned s = 0;
#pragma unroll
    for (int i = 0; i < 4; i++) { int b = base + i; if (b < nbins) s += cnt[b]; }
    sh[threadIdx.x] = s;
    __syncthreads();
    for (int off = 128; off; off >>= 1) {
        if (threadIdx.x < off) sh[threadIdx.x] += sh[threadIdx.x + off];
        __syncthreads();
    }
    if (threadIdx.x == 0) chunkSum[blockIdx.x] = sh[0];
}

__global__ void scanChunksK(const unsigned* __restrict__ chunkSum, unsigned* __restrict__ chunkOff,
                            int nchunks, unsigned* __restrict__ totalOut) {
    if (threadIdx.x == 0) {
        unsigned run = 0;
        for (int i = 0; i < nchunks; i++) { chunkOff[i] = run; run += chunkSum[i]; }
        *totalOut = run;
    }
}

__global__ __launch_bounds__(256) void scanFinalK(const unsigned* __restrict__ cnt,
                                                  const unsigned* __restrict__ chunkOff,
                                                  unsigned* __restrict__ rowptr, int nbins) {
    __shared__ unsigned sh[256];
    int t = threadIdx.x;
    int base = blockIdx.x * SCAN_CHUNK + t * 4;
    unsigned c[4], s = 0;
#pragma unroll
    for (int i = 0; i < 4; i++) { int b = base + i; c[i] = (b < nbins) ? cnt[b] : 0u; s += c[i]; }
    sh[t] = s;
    __syncthreads();
    for (int off = 1; off < 256; off <<= 1) {
        unsigned v = (t >= off) ? sh[t - off] : 0u;
        __syncthreads();
        sh[t] += v;
        __syncthreads();
    }
    unsigned basep = chunkOff[blockIdx.x] + sh[t] - s;
#pragma unroll
    for (int i = 0; i < 4; i++) {
        int b = base + i;
        if (b < nbins) { rowptr[b] = basep; basep += c[i]; }
    }
}

__global__ __launch_bounds__(256) void scatterFillK(const int* __restrict__ src,
                                                    const int* __restrict__ dst,
                                                    const unsigned* __restrict__ rowptr,
                                                    unsigned* __restrict__ fill,
                                                    int* __restrict__ sortedSrc) {
    int e = blockIdx.x * 256 + threadIdx.x;
    if (e >= E0) return;
    int d = dst[e];
    unsigned p = rowptr[d] + atomicAdd(&fill[d], 1u);
    sortedSrc[p] = src[e];
}

__global__ __launch_bounds__(256) void iotaK(int* o, int n) {
    int i = blockIdx.x * 256 + threadIdx.x;
    if (i < n) o[i] = i;
}

// ---------- segmented aggregation ----------
__global__ __launch_bounds__(256) void aggSegK(const float* __restrict__ x,
                                               const int* __restrict__ srcCur,
                                               const unsigned* __restrict__ rowptr,
                                               const int* __restrict__ orig,
                                               float* __restrict__ agg, int n) {
    int g = blockIdx.x * 8 + (threadIdx.x >> 5);
    int q = threadIdx.x & 31;
    if (g >= n) return;
    int d = orig[g];
    unsigned e0 = rowptr[d], e1 = rowptr[d + 1];
    float4 acc = make_float4(0.f, 0.f, 0.f, 0.f);
    for (unsigned e = e0; e < e1; e++) {
        int s = srcCur[e];
        if (s < 0) continue;
        float4 v = *(const float4*)(x + (size_t)s * F + q * 4);
        acc.x += v.x; acc.y += v.y; acc.z += v.z; acc.w += v.w;
    }
    *(float4*)(agg + (size_t)g * F + q * 4) = acc;
}

__global__ __launch_bounds__(256) void buildOrigK(const int* __restrict__ origIn,
                                                  const int* __restrict__ nidx,
                                                  int* __restrict__ origOut, int n) {
    int i = blockIdx.x * 256 + threadIdx.x;
    if (i < n) { int ni = nidx[i]; if (ni >= 0) origOut[ni] = origIn[i]; }
}

__global__ __launch_bounds__(256) void remapSrcK(const int* __restrict__ srcIn,
                                                 const int* __restrict__ nidx,
                                                 int* __restrict__ srcOut) {
    int e = blockIdx.x * 256 + threadIdx.x;
    if (e >= E0) return;
    int s = srcIn[e];
    srcOut[e] = (s >= 0) ? nidx[s] : -1;
}

// ---------- fused conv: out = relu(agg@Wr.T + x@Wroot.T + br) ----------
#define BM 128
#define BKC 16
__global__ __launch_bounds__(256) void convK(const float* __restrict__ agg,
                                             const float* __restrict__ x,
                                             const float* __restrict__ Wr,
                                             const float* __restrict__ Wroot,
                                             const float* __restrict__ br,
                                             float* __restrict__ out, int n) {
    __shared__ float As[BKC][BM + 1];
    __shared__ float Ws[BKC][BM + 1];
    int tid = threadIdx.x;
    int bm = blockIdx.x * BM;
    int rg = tid >> 4, cg = tid & 15;
    int lr = tid >> 2, kq = tid & 3;
    float acc[8][8];
#pragma unroll
    for (int i = 0; i < 8; i++)
#pragma unroll
        for (int j = 0; j < 8; j++) acc[i][j] = 0.f;

    for (int ph = 0; ph < 2; ph++) {
        const float* A = ph ? x : agg;
        const float* W = ph ? Wroot : Wr;
        for (int kk = 0; kk < F; kk += BKC) {
#pragma unroll
            for (int h = 0; h < 2; h++) {
                int ar = lr + h * 64;
                float4 v = make_float4(0.f, 0.f, 0.f, 0.f);
                if (bm + ar < n) v = *(const float4*)(A + (size_t)(bm + ar) * F + kk + kq * 4);
                As[kq * 4 + 0][ar] = v.x; As[kq * 4 + 1][ar] = v.y;
                As[kq * 4 + 2][ar] = v.z; As[kq * 4 + 3][ar] = v.w;
                float4 wv = *(const float4*)(W + (size_t)ar * F + kk + kq * 4);
                Ws[kq * 4 + 0][ar] = wv.x; Ws[kq * 4 + 1][ar] = wv.y;
                Ws[kq * 4 + 2][ar] = wv.z; Ws[kq * 4 + 3][ar] = wv.w;
            }
            __syncthreads();
#pragma unroll
            for (int k = 0; k < BKC; k++) {
                float a[8], w[8];
#pragma unroll
                for (int i = 0; i < 8; i++) a[i] = As[k][rg + 16 * i];
#pragma unroll
                for (int j = 0; j < 8; j++) w[j] = Ws[k][cg + 16 * j];
#pragma unroll
                for (int i = 0; i < 8; i++)
#pragma unroll
                    for (int j = 0; j < 8; j++) acc[i][j] = fmaf(a[i], w[j], acc[i][j]);
            }
            __syncthreads();
        }
    }
#pragma unroll
    for (int i = 0; i < 8; i++) {
        int row = bm + rg + 16 * i;
        if (row < n) {
#pragma unroll
            for (int j = 0; j < 8; j++) {
                int col = cg + 16 * j;
                out[(size_t)row * F + col] = fmaxf(acc[i][j] + br[col], 0.f);
            }
        }
    }
}

// ---------- score ----------
__global__ __launch_bounds__(256) void scoreK(const float* __restrict__ h,
                                              const float* __restrict__ pw,
                                              float* __restrict__ sc,
                                              unsigned* __restrict__ keys, int n) {
    int wv = threadIdx.x >> 6, lane = threadIdx.x & 63;
    int row = blockIdx.x * 4 + wv;
    if (row >= n) return;
    float p0 = pw[lane], p1 = pw[lane + 64];
    float h0 = h[(size_t)row * F + lane], h1 = h[(size_t)row * F + lane + 64];
    float d = h0 * p0 + h1 * p1;
    float q = p0 * p0 + p1 * p1;
    for (int off = 32; off; off >>= 1) {
        d += __shfl_down(d, off);
        q += __shfl_down(q, off);
    }
    if (lane == 0) {
        float s = tanhf(d / sqrtf(q));
        sc[row] = s;
        keys[row] = fkey(s);
    }
}

// ---------- radix select ----------
__global__ void initSelK(unsigned* hist, unsigned* st, int k) {
    hist[threadIdx.x] = 0;
    if (threadIdx.x == 0) { st[0] = 0u; st[1] = (unsigned)k; }
}

__global__ __launch_bounds__(256) void histK(const unsigned* __restrict__ keys, int n,
                                             int p, const unsigned* __restrict__ st,
                                             unsigned* __restrict__ hist) {
    __shared__ unsigned lh[256];
    lh[threadIdx.x] = 0;
    __syncthreads();
    unsigned prefix = st[0];
    int i = blockIdx.x * 256 + threadIdx.x;
    if (i < n) {
        unsigned key = keys[i];
        bool m = (p == 0) || ((key >> (32 - 8 * p)) == (prefix >> (32 - 8 * p)));
        if (m) atomicAdd(&lh[(key >> (24 - 8 * p)) & 255u], 1u);
    }
    __syncthreads();
    if (lh[threadIdx.x]) atomicAdd(&hist[threadIdx.x], lh[threadIdx.x]);
}

__global__ void selectK(unsigned* hist, unsigned* st, int p) {
    __shared__ unsigned h[256];
    h[threadIdx.x] = hist[threadIdx.x];
    __syncthreads();
    if (threadIdx.x == 0) {
        unsigned krem = st[1], cum = 0;
        for (int b = 255; b >= 0; b--) {
            unsigned c = h[b];
            if (cum + c >= krem) {
                st[0] |= ((unsigned)b) << (24 - 8 * p);
                st[1] = krem - cum;
                break;
            }
            cum += c;
        }
    }
    __syncthreads();
    hist[threadIdx.x] = 0;
}

// ---------- exact ordered selection ----------
__global__ __launch_bounds__(256) void countsK(const unsigned* __restrict__ keys, int n,
                                               const unsigned* __restrict__ st,
                                               int* __restrict__ bGT, int* __restrict__ bEQ) {
    __shared__ int cg_, ce_;
    if (threadIdx.x == 0) { cg_ = 0; ce_ = 0; }
    __syncthreads();
    unsigned t = st[0];
    int g = 0, e = 0;
    for (int it = 0; it < 4; it++) {
        int i = blockIdx.x * 1024 + it * 256 + threadIdx.x;
        if (i < n) {
            unsigned k = keys[i];
            g += (k > t);
            e += (k == t);
        }
    }
    atomicAdd(&cg_, g);
    atomicAdd(&ce_, e);
    __syncthreads();
    if (threadIdx.x == 0) { bGT[blockIdx.x] = cg_; bEQ[blockIdx.x] = ce_; }
}

__global__ void scanK(const int* bGT, const int* bEQ, int* sGT, int* sEQ, int nb) {
    if (threadIdx.x == 0 && blockIdx.x == 0) {
        int g = 0, e = 0;
        for (int b = 0; b < nb; b++) {
            sGT[b] = g; sEQ[b] = e;
            g += bGT[b]; e += bEQ[b];
        }
    }
}

__global__ __launch_bounds__(256) void markK(const unsigned* __restrict__ keys, int n,
                                             const unsigned* __restrict__ st,
                                             const int* __restrict__ sGT,
                                             const int* __restrict__ sEQ,
                                             int* __restrict__ nidx) {
    __shared__ int wG[4], wE[4];
    __shared__ int runG, runE;
    int tid = threadIdx.x, wv = tid >> 6, lane = tid & 63;
    if (tid == 0) { runG = 0; runE = 0; }
    unsigned t = st[0];
    int needEq = (int)st[1];
    int gOff = sGT[blockIdx.x], eOff = sEQ[blockIdx.x];
    unsigned long long mlt = (((unsigned long long)1) << lane) - 1ull;
    __syncthreads();
    for (int it = 0; it < 4; it++) {
        int i = blockIdx.x * 1024 + it * 256 + tid;
        bool inb = i < n;
        unsigned k = inb ? keys[i] : 0u;
        bool pG = inb && (k > t), pE = inb && (k == t);
        unsigned long long bG = __ballot(pG), bE = __ballot(pE);
        int lpG = __popcll(bG & mlt), lpE = __popcll(bE & mlt);
        if (lane == 0) { wG[wv] = __popcll(bG); wE[wv] = __popcll(bE); }
        __syncthreads();
        int woG = 0, woE = 0;
        for (int w = 0; w < wv; w++) { woG += wG[w]; woE += wE[w]; }
        int gB = gOff + runG + woG + lpG;
        int eB = eOff + runE + woE + lpE;
        int ni = -1;
        if (pG) ni = gB + (eB < needEq ? eB : needEq);
        else if (pE && eB < needEq) ni = gB + eB;
        if (inb) nidx[i] = ni;
        __syncthreads();
        if (tid == 0) {
            runG += wG[0] + wG[1] + wG[2] + wG[3];
            runE += wE[0] + wE[1] + wE[2] + wE[3];
        }
        __syncthreads();
    }
}

// ---------- gather+scale ----------
__global__ __launch_bounds__(256) void gatherK(const float* __restrict__ h,
                                               const float* __restrict__ sc,
                                               const int* __restrict__ nidx,
                                               float* __restrict__ out, int n) {
    int t = blockIdx.x * 256 + threadIdx.x;
    int i = t >> 5, q = t & 31;
    if (i >= n) return;
    int ni = nidx[i];
    if (ni < 0) return;
    float s = sc[i];
    float4 v = *(const float4*)(h + (size_t)i * F + q * 4);
    v.x *= s; v.y *= s; v.z *= s; v.w *= s;
    *(float4*)(out + (size_t)ni * F + q * 4) = v;
}

// ---------- readout: 3-stage max/sum reduction ----------
__global__ __launch_bounds__(128) void rpartK(const float* __restrict__ x, int k,
                                              float* __restrict__ pmax, float* __restrict__ psum) {
    int f = threadIdx.x;
    float m = -INFINITY, s = 0.f;
    for (int row = blockIdx.x; row < k; row += gridDim.x) {
        float v = x[(size_t)row * F + f];
        m = fmaxf(m, v);
        s += v;
    }
    pmax[(size_t)blockIdx.x * F + f] = m;
    psum[(size_t)blockIdx.x * F + f] = s;
}

__global__ __launch_bounds__(128) void rmidK(const float* __restrict__ pmax,
                                             const float* __restrict__ psum,
                                             float* __restrict__ mmax,
                                             float* __restrict__ msum) {
    int f = threadIdx.x;
    int b0 = blockIdx.x * (RPB / RMID);
    float m = -INFINITY, s = 0.f;
#pragma unroll
    for (int i = 0; i < RPB / RMID; i++) {
        m = fmaxf(m, pmax[(size_t)(b0 + i) * F + f]);
        s += psum[(size_t)(b0 + i) * F + f];
    }
    mmax[(size_t)blockIdx.x * F + f] = m;
    msum[(size_t)blockIdx.x * F + f] = s;
}

__global__ __launch_bounds__(128) void rfinalK(const float* __restrict__ mmax,
                                               const float* __restrict__ msum, int k,
                                               float* __restrict__ r) {
    int f = threadIdx.x;
    float m = -INFINITY, s = 0.f;
    for (int b = 0; b < RMID; b++) {
        m = fmaxf(m, mmax[(size_t)b * F + f]);
        s += msum[(size_t)b * F + f];
    }
    r[f] += m;
    r[F + f] += s / (float)k;
}

// ---------- final MLP ----------
__global__ __launch_bounds__(256) void mlpK(const float* __restrict__ r,
                                            const float* __restrict__ W1, const float* __restrict__ b1,
                                            const float* __restrict__ W2, const float* __restrict__ b2,
                                            const float* __restrict__ W3, const float* __restrict__ b3,
                                            float* __restrict__ out) {
    __shared__ float z0[256], z1[128], z2[64];
    int t = threadIdx.x;
    z0[t] = r[t];
    __syncthreads();
    if (t < 128) {
        float a = b1[t];
        for (int kk = 0; kk < 256; kk++) a = fmaf(W1[t * 256 + kk], z0[kk], a);
        z1[t] = fmaxf(a, 0.f);
    }
    __syncthreads();
    if (t < 64) {
        float a = b2[t];
        for (int kk = 0; kk < 128; kk++) a = fmaf(W2[t * 128 + kk], z1[kk], a);
        z2[t] = fmaxf(a, 0.f);
    }
    __syncthreads();
    if (t < 2) {
        float a = b3[t];
        for (int kk = 0; kk < 64; kk++) a = fmaf(W3[t * 64 + kk], z2[kk], a);
        out[t] = a;
    }
}

extern "C" void kernel_launch(void* const* d_in, const int* in_sizes, int n_in,
                              void* d_out, int out_size, void* d_ws, size_t ws_size,
                              hipStream_t stream) {
    const float* x = (const float*)d_in[0];
    const int* ei = (const int*)d_in[1];
    const float* Wr[3]    = { (const float*)d_in[2],  (const float*)d_in[6],  (const float*)d_in[10] };
    const float* br[3]    = { (const float*)d_in[3],  (const float*)d_in[7],  (const float*)d_in[11] };
    const float* Wroot[3] = { (const float*)d_in[4],  (const float*)d_in[8],  (const float*)d_in[12] };
    const float* pw[3]    = { (const float*)d_in[5],  (const float*)d_in[9],  (const float*)d_in[13] };
    const float* W1 = (const float*)d_in[14];
    const float* b1 = (const float*)d_in[15];
    const float* W2 = (const float*)d_in[16];
    const float* b2 = (const float*)d_in[17];
    const float* W3 = (const float*)d_in[18];
    const float* b3 = (const float*)d_in[19];
    float* out = (float*)d_out;
    char* w = (char*)d_ws;

    size_t o = 0;
    auto alc = [&](size_t bytes) { size_t r = o; o += (bytes + 255) & ~(size_t)255; return r; };
    float*    bufA   = (float*)(w + alc((size_t)N0 * F * 4));
    float*    bufB   = (float*)(w + alc((size_t)KP1 * F * 4));
    float*    agg    = (float*)(w + alc((size_t)N0 * F * 4));
    float*    sc     = (float*)(w + alc((size_t)N0 * 4));
    unsigned* keys   = (unsigned*)(w + alc((size_t)N0 * 4));
    int*      nidx   = (int*)(w + alc((size_t)N0 * 4));
    int*      sSrc0  = (int*)(w + alc((size_t)E0 * 4));
    int*      srcCA  = (int*)(w + alc((size_t)E0 * 4));
    int*      srcCB  = (int*)(w + alc((size_t)E0 * 4));
    unsigned* cnt    = (unsigned*)(w + alc((size_t)N0 * 4));
    unsigned* rowptr = (unsigned*)(w + alc((size_t)(N0 + 1) * 4));
    int*      origA  = (int*)(w + alc((size_t)N0 * 4));
    int*      origB  = (int*)(w + alc((size_t)N0 * 4));
    unsigned* chS    = (unsigned*)(w + alc(NCHUNK * 4));
    unsigned* chO    = (unsigned*)(w + alc(NCHUNK * 4));
    unsigned* hist   = (unsigned*)(w + alc(256 * 4));
    unsigned* st     = (unsigned*)(w + alc(64));
    int*      bGT    = (int*)(w + alc(128 * 4));
    int*      bEQ    = (int*)(w + alc(128 * 4));
    int*      sGT    = (int*)(w + alc(128 * 4));
    int*      sEQ    = (int*)(w + alc(128 * 4));
    float*    r      = (float*)(w + alc(256 * 4));
    float*    pmax   = (float*)(w + alc((size_t)RPB * F * 4));
    float*    psum   = (float*)(w + alc((size_t)RPB * F * 4));
    float*    mmax   = (float*)(w + alc((size_t)RMID * F * 4));
    float*    msum   = (float*)(w + alc((size_t)RMID * F * 4));
    if (o > ws_size) return;

    const int* srcOrig = ei;
    const int* dstOrig = ei + E0;

    // ----- build dst-sorted CSR once (stays valid for all layers: nidx is monotone) -----
    hipMemsetAsync(cnt, 0, (size_t)N0 * 4, stream);
    histDstK<<<(E0 + 255) / 256, 256, 0, stream>>>(dstOrig, cnt);
    scanReduceK<<<NCHUNK, 256, 0, stream>>>(cnt, chS, N0);
    scanChunksK<<<1, 1, 0, stream>>>(chS, chO, NCHUNK, rowptr + N0);
    scanFinalK<<<NCHUNK, 256, 0, stream>>>(cnt, chO, rowptr, N0);
    hipMemsetAsync(cnt, 0, (size_t)N0 * 4, stream);
    scatterFillK<<<(E0 + 255) / 256, 256, 0, stream>>>(srcOrig, dstOrig, rowptr, cnt, sSrc0);
    iotaK<<<(N0 + 255) / 256, 256, 0, stream>>>(origA, N0);

    hipMemsetAsync(r, 0, 256 * 4, stream);

    const int ns[3] = { N0, KP1, KP2 };
    const int ks[3] = { KP1, KP2, KP3 };
    const int* srcCur[3] = { sSrc0, srcCA, srcCB };
    int* srcNext[3] = { srcCA, srcCB, nullptr };
    const int* origCur[3] = { origA, origB, origA };
    int* origNext[3] = { origB, origA, nullptr };

    for (int L = 0; L < 3; L++) {
        int n = ns[L], k = ks[L];
        const float* xin = (L == 0) ? x : bufB;

        aggSegK<<<(n + 7) / 8, 256, 0, stream>>>(xin, srcCur[L], rowptr, origCur[L], agg, n);
        convK<<<(n + BM - 1) / BM, 256, 0, stream>>>(agg, xin, Wr[L], Wroot[L], br[L], bufA, n);
        scoreK<<<(n + 3) / 4, 256, 0, stream>>>(bufA, pw[L], sc, keys, n);

        initSelK<<<1, 256, 0, stream>>>(hist, st, k);
        for (int p = 0; p < 4; p++) {
            histK<<<(n + 255) / 256, 256, 0, stream>>>(keys, n, p, st, hist);
            selectK<<<1, 256, 0, stream>>>(hist, st, p);
        }
        int nb = (n + 1023) / 1024;
        countsK<<<nb, 256, 0, stream>>>(keys, n, st, bGT, bEQ);
        scanK<<<1, 1, 0, stream>>>(bGT, bEQ, sGT, sEQ, nb);
        markK<<<nb, 256, 0, stream>>>(keys, n, st, sGT, sEQ, nidx);

        gatherK<<<(n * 32 + 255) / 256, 256, 0, stream>>>(bufA, sc, nidx, bufB, n);
        if (L < 2) {
            buildOrigK<<<(n + 255) / 256, 256, 0, stream>>>(origCur[L], nidx, origNext[L], n);
            remapSrcK<<<(E0 + 255) / 256, 256, 0, stream>>>(srcCur[L], nidx, srcNext[L]);
        }

        rpartK<<<RPB, 128, 0, stream>>>(bufB, k, pmax, psum);
        rmidK<<<RMID, 128, 0, stream>>>(pmax, psum, mmax, msum);
        rfinalK<<<1, 128, 0, stream>>>(mmax, msum, k, r);
    }

    mlpK<<<1, 256, 0, stream>>>(r, W1, b1, W2, b2, W3, b3, out);
}

// Round 6
// 668.582 us; speedup vs baseline: 4.6823x; 1.3943x over previous
//
#include <hip/hip_runtime.h>
#include <hip/hip_bf16.h>
#include <math.h>

#define N0 100000
#define E0 600000
#define KP1 80000
#define KP2 64000
#define KP3 51200
#define F 128
#define RPB 2048
#define RMID 128
#define SCAN_CHUNK 1024
#define NCHUNK ((N0 + SCAN_CHUNK - 1) / SCAN_CHUNK)

typedef __attribute__((ext_vector_type(8))) short short8;
typedef __attribute__((ext_vector_type(4))) float f32x4;

// ---------- helpers ----------
__device__ __forceinline__ unsigned fkey(float f) {
    unsigned u = __float_as_uint(f);
    return u ^ ((u & 0x80000000u) ? 0xFFFFFFFFu : 0x80000000u);
}
__device__ __forceinline__ unsigned short f2b(float f) {
    __hip_bfloat16 h = __float2bfloat16(f);
    return *(unsigned short*)&h;
}
__device__ __forceinline__ float b2f(unsigned short u) {
    __hip_bfloat16 h;
    *(unsigned short*)&h = u;
    return __bfloat162float(h);
}

// ---------- conversions (once per launch) ----------
__global__ __launch_bounds__(256) void cvt4K(const float* __restrict__ in,
                                             unsigned short* __restrict__ out, int n4) {
    int i = blockIdx.x * 256 + threadIdx.x;
    if (i >= n4) return;
    float4 v = *(const float4*)(in + (size_t)i * 4);
    *(ushort4*)(out + (size_t)i * 4) = make_ushort4(f2b(v.x), f2b(v.y), f2b(v.z), f2b(v.w));
}

__global__ __launch_bounds__(256) void cvtWAllK(const float* __restrict__ a0, const float* __restrict__ a1,
                                                const float* __restrict__ a2, const float* __restrict__ a3,
                                                const float* __restrict__ a4, const float* __restrict__ a5,
                                                unsigned short* __restrict__ o) {
    int m = blockIdx.y;
    const float* src = (m == 0) ? a0 : (m == 1) ? a1 : (m == 2) ? a2 : (m == 3) ? a3 : (m == 4) ? a4 : a5;
    int i = blockIdx.x * 256 + threadIdx.x;   // 4096 threads, 4 elems each
    float4 v = *(const float4*)(src + (size_t)i * 4);
    *(ushort4*)(o + (size_t)m * 16384 + (size_t)i * 4) = make_ushort4(f2b(v.x), f2b(v.y), f2b(v.z), f2b(v.w));
}

// ---------- CSR build (once per launch) ----------
__global__ __launch_bounds__(256) void histDstK(const int* __restrict__ dst, unsigned* __restrict__ cnt) {
    int e = blockIdx.x * 256 + threadIdx.x;
    if (e < E0) atomicAdd(&cnt[dst[e]], 1u);
}

__global__ __launch_bounds__(256) void scanReduceK(const unsigned* __restrict__ cnt,
                                                   unsigned* __restrict__ chunkSum, int nbins) {
    __shared__ unsigned sh[256];
    int base = blockIdx.x * SCAN_CHUNK + threadIdx.x * 4;
    unsigned s = 0;
#pragma unroll
    for (int i = 0; i < 4; i++) { int b = base + i; if (b < nbins) s += cnt[b]; }
    sh[threadIdx.x] = s;
    __syncthreads();
    for (int off = 128; off; off >>= 1) {
        if (threadIdx.x < off) sh[threadIdx.x] += sh[threadIdx.x + off];
        __syncthreads();
    }
    if (threadIdx.x == 0) chunkSum[blockIdx.x] = sh[0];
}

__global__ void scanChunksK(const unsigned* __restrict__ chunkSum, unsigned* __restrict__ chunkOff,
                            int nchunks, unsigned* __restrict__ totalOut) {
    if (threadIdx.x == 0) {
        unsigned run = 0;
        for (int i = 0; i < nchunks; i++) { chunkOff[i] = run; run += chunkSum[i]; }
        *totalOut = run;
    }
}

__global__ __launch_bounds__(256) void scanFinalK(const unsigned* __restrict__ cnt,
                                                  const unsigned* __restrict__ chunkOff,
                                                  unsigned* __restrict__ rowptr, int nbins) {
    __shared__ unsigned sh[256];
    int t = threadIdx.x;
    int base = blockIdx.x * SCAN_CHUNK + t * 4;
    unsigned c[4], s = 0;
#pragma unroll
    for (int i = 0; i < 4; i++) { int b = base + i; c[i] = (b < nbins) ? cnt[b] : 0u; s += c[i]; }
    sh[t] = s;
    __syncthreads();
    for (int off = 1; off < 256; off <<= 1) {
        unsigned v = (t >= off) ? sh[t - off] : 0u;
        __syncthreads();
        sh[t] += v;
        __syncthreads();
    }
    unsigned basep = chunkOff[blockIdx.x] + sh[t] - s;
#pragma unroll
    for (int i = 0; i < 4; i++) {
        int b = base + i;
        if (b < nbins) { rowptr[b] = basep; basep += c[i]; }
    }
}

__global__ __launch_bounds__(256) void scatterFillK(const int* __restrict__ src,
                                                    const int* __restrict__ dst,
                                                    const unsigned* __restrict__ rowptr,
                                                    unsigned* __restrict__ fill,
                                                    int* __restrict__ sortedSrc) {
    int e = blockIdx.x * 256 + threadIdx.x;
    if (e >= E0) return;
    int d = dst[e];
    unsigned p = rowptr[d] + atomicAdd(&fill[d], 1u);
    sortedSrc[p] = src[e];
}

__global__ __launch_bounds__(256) void iotaK(int* o, int n) {
    int i = blockIdx.x * 256 + threadIdx.x;
    if (i < n) o[i] = i;
}

// ---------- segmented aggregation (bf16 in, fp32 accum, bf16 out) ----------
__global__ __launch_bounds__(256) void aggSegB(const unsigned short* __restrict__ x,
                                               const int* __restrict__ srcCur,
                                               const unsigned* __restrict__ rowptr,
                                               const int* __restrict__ orig,
                                               unsigned short* __restrict__ agg, int n) {
    int g = blockIdx.x * 8 + (threadIdx.x >> 5);
    int q = threadIdx.x & 31;
    if (g >= n) return;
    int d = orig[g];
    unsigned e0 = rowptr[d], e1 = rowptr[d + 1];
    float a0 = 0.f, a1 = 0.f, a2 = 0.f, a3 = 0.f;
    for (unsigned e = e0; e < e1; e++) {
        int s = srcCur[e];
        if (s < 0) continue;
        ushort4 v = *(const ushort4*)(x + (size_t)s * F + q * 4);
        a0 += b2f(v.x); a1 += b2f(v.y); a2 += b2f(v.z); a3 += b2f(v.w);
    }
    *(ushort4*)(agg + (size_t)g * F + q * 4) = make_ushort4(f2b(a0), f2b(a1), f2b(a2), f2b(a3));
}

__global__ __launch_bounds__(256) void buildOrigK(const int* __restrict__ origIn,
                                                  const int* __restrict__ nidx,
                                                  int* __restrict__ origOut, int n) {
    int i = blockIdx.x * 256 + threadIdx.x;
    if (i < n) { int ni = nidx[i]; if (ni >= 0) origOut[ni] = origIn[i]; }
}

__global__ __launch_bounds__(256) void remapSrcK(const int* __restrict__ srcIn,
                                                 const int* __restrict__ nidx,
                                                 int* __restrict__ srcOut) {
    int e = blockIdx.x * 256 + threadIdx.x;
    if (e >= E0) return;
    int s = srcIn[e];
    srcOut[e] = (s >= 0) ? nidx[s] : -1;
}

// ---------- MFMA conv: out = relu([agg|x] @ [Wr|Wroot]^T + br), bf16 in / fp32 out ----------
#define CPAD 40   // LDS row stride in shorts (32 data + 8 pad) -> conflict-free b128 reads
__global__ __launch_bounds__(256) void convM(const unsigned short* __restrict__ A0,
                                             const unsigned short* __restrict__ A1,
                                             const unsigned short* __restrict__ W0,
                                             const unsigned short* __restrict__ W1,
                                             const float* __restrict__ br,
                                             float* __restrict__ out, int n) {
    __shared__ unsigned short As[128 * CPAD];
    __shared__ unsigned short Bs[128 * CPAD];
    int tid = threadIdx.x;
    int w = tid >> 6, l = tid & 63;
    int r = l & 15, g = l >> 4;
    int bm = blockIdx.x * 128;
    int srow = tid >> 2, q4 = tid & 3;

    f32x4 acc[2][8];
#pragma unroll
    for (int m = 0; m < 2; m++)
#pragma unroll
        for (int c = 0; c < 8; c++) acc[m][c] = (f32x4){0.f, 0.f, 0.f, 0.f};

    for (int ph = 0; ph < 2; ph++) {
        const unsigned short* A = ph ? A1 : A0;
        const unsigned short* W = ph ? W1 : W0;
        for (int kk = 0; kk < 128; kk += 32) {
            __syncthreads();
#pragma unroll
            for (int h2 = 0; h2 < 2; h2++) {
                int rr = srow + h2 * 64;
                uint4 av = make_uint4(0u, 0u, 0u, 0u);
                if (bm + rr < n) av = *(const uint4*)(A + (size_t)(bm + rr) * F + kk + q4 * 8);
                *(uint4*)(&As[rr * CPAD + q4 * 8]) = av;
                uint4 wv = *(const uint4*)(W + (size_t)rr * F + kk + q4 * 8);
                *(uint4*)(&Bs[rr * CPAD + q4 * 8]) = wv;
            }
            __syncthreads();
            short8 af[2], bf[8];
#pragma unroll
            for (int m = 0; m < 2; m++)
                af[m] = *(const short8*)(&As[(w * 32 + m * 16 + r) * CPAD + g * 8]);
#pragma unroll
            for (int c = 0; c < 8; c++)
                bf[c] = *(const short8*)(&Bs[(c * 16 + r) * CPAD + g * 8]);
#pragma unroll
            for (int m = 0; m < 2; m++)
#pragma unroll
                for (int c = 0; c < 8; c++)
                    acc[m][c] = __builtin_amdgcn_mfma_f32_16x16x32_bf16(af[m], bf[c], acc[m][c], 0, 0, 0);
        }
    }

#pragma unroll
    for (int c = 0; c < 8; c++) {
        int col = c * 16 + r;
        float bias = br[col];
#pragma unroll
        for (int m = 0; m < 2; m++) {
#pragma unroll
            for (int j = 0; j < 4; j++) {
                int row = bm + w * 32 + m * 16 + g * 4 + j;
                if (row < n) out[(size_t)row * F + col] = fmaxf(acc[m][c][j] + bias, 0.f);
            }
        }
    }
}

// ---------- score (fp32 bufA) ----------
__global__ __launch_bounds__(256) void scoreK(const float* __restrict__ h,
                                              const float* __restrict__ pw,
                                              float* __restrict__ sc,
                                              unsigned* __restrict__ keys, int n) {
    int wv = threadIdx.x >> 6, lane = threadIdx.x & 63;
    int row = blockIdx.x * 4 + wv;
    if (row >= n) return;
    float p0 = pw[lane], p1 = pw[lane + 64];
    float h0 = h[(size_t)row * F + lane], h1 = h[(size_t)row * F + lane + 64];
    float d = h0 * p0 + h1 * p1;
    float q = p0 * p0 + p1 * p1;
    for (int off = 32; off; off >>= 1) {
        d += __shfl_down(d, off);
        q += __shfl_down(q, off);
    }
    if (lane == 0) {
        float s = tanhf(d / sqrtf(q));
        sc[row] = s;
        keys[row] = fkey(s);
    }
}

// ---------- radix select ----------
__global__ void initSelK(unsigned* hist, unsigned* st, int k) {
    hist[threadIdx.x] = 0;
    if (threadIdx.x == 0) { st[0] = 0u; st[1] = (unsigned)k; }
}

__global__ __launch_bounds__(256) void histK(const unsigned* __restrict__ keys, int n,
                                             int p, const unsigned* __restrict__ st,
                                             unsigned* __restrict__ hist) {
    __shared__ unsigned lh[256];
    lh[threadIdx.x] = 0;
    __syncthreads();
    unsigned prefix = st[0];
    int i = blockIdx.x * 256 + threadIdx.x;
    if (i < n) {
        unsigned key = keys[i];
        bool m = (p == 0) || ((key >> (32 - 8 * p)) == (prefix >> (32 - 8 * p)));
        if (m) atomicAdd(&lh[(key >> (24 - 8 * p)) & 255u], 1u);
    }
    __syncthreads();
    if (lh[threadIdx.x]) atomicAdd(&hist[threadIdx.x], lh[threadIdx.x]);
}

__global__ void selectK(unsigned* hist, unsigned* st, int p) {
    __shared__ unsigned h[256];
    h[threadIdx.x] = hist[threadIdx.x];
    __syncthreads();
    if (threadIdx.x == 0) {
        unsigned krem = st[1], cum = 0;
        for (int b = 255; b >= 0; b--) {
            unsigned c = h[b];
            if (cum + c >= krem) {
                st[0] |= ((unsigned)b) << (24 - 8 * p);
                st[1] = krem - cum;
                break;
            }
            cum += c;
        }
    }
    __syncthreads();
    hist[threadIdx.x] = 0;
}

// ---------- exact ordered selection ----------
__global__ __launch_bounds__(256) void countsK(const unsigned* __restrict__ keys, int n,
                                               const unsigned* __restrict__ st,
                                               int* __restrict__ bGT, int* __restrict__ bEQ) {
    __shared__ int cg_, ce_;
    if (threadIdx.x == 0) { cg_ = 0; ce_ = 0; }
    __syncthreads();
    unsigned t = st[0];
    int g = 0, e = 0;
    for (int it = 0; it < 4; it++) {
        int i = blockIdx.x * 1024 + it * 256 + threadIdx.x;
        if (i < n) {
            unsigned k = keys[i];
            g += (k > t);
            e += (k == t);
        }
    }
    atomicAdd(&cg_, g);
    atomicAdd(&ce_, e);
    __syncthreads();
    if (threadIdx.x == 0) { bGT[blockIdx.x] = cg_; bEQ[blockIdx.x] = ce_; }
}

__global__ void scanK(const int* bGT, const int* bEQ, int* sGT, int* sEQ, int nb) {
    if (threadIdx.x == 0 && blockIdx.x == 0) {
        int g = 0, e = 0;
        for (int b = 0; b < nb; b++) {
            sGT[b] = g; sEQ[b] = e;
            g += bGT[b]; e += bEQ[b];
        }
    }
}

__global__ __launch_bounds__(256) void markK(const unsigned* __restrict__ keys, int n,
                                             const unsigned* __restrict__ st,
                                             const int* __restrict__ sGT,
                                             const int* __restrict__ sEQ,
                                             int* __restrict__ nidx) {
    __shared__ int wG[4], wE[4];
    __shared__ int runG, runE;
    int tid = threadIdx.x, wv = tid >> 6, lane = tid & 63;
    if (tid == 0) { runG = 0; runE = 0; }
    unsigned t = st[0];
    int needEq = (int)st[1];
    int gOff = sGT[blockIdx.x], eOff = sEQ[blockIdx.x];
    unsigned long long mlt = (((unsigned long long)1) << lane) - 1ull;
    __syncthreads();
    for (int it = 0; it < 4; it++) {
        int i = blockIdx.x * 1024 + it * 256 + tid;
        bool inb = i < n;
        unsigned k = inb ? keys[i] : 0u;
        bool pG = inb && (k > t), pE = inb && (k == t);
        unsigned long long bG = __ballot(pG), bE = __ballot(pE);
        int lpG = __popcll(bG & mlt), lpE = __popcll(bE & mlt);
        if (lane == 0) { wG[wv] = __popcll(bG); wE[wv] = __popcll(bE); }
        __syncthreads();
        int woG = 0, woE = 0;
        for (int w = 0; w < wv; w++) { woG += wG[w]; woE += wE[w]; }
        int gB = gOff + runG + woG + lpG;
        int eB = eOff + runE + woE + lpE;
        int ni = -1;
        if (pG) ni = gB + (eB < needEq ? eB : needEq);
        else if (pE && eB < needEq) ni = gB + eB;
        if (inb) nidx[i] = ni;
        __syncthreads();
        if (tid == 0) {
            runG += wG[0] + wG[1] + wG[2] + wG[3];
            runE += wE[0] + wE[1] + wE[2] + wE[3];
        }
        __syncthreads();
    }
}

// ---------- gather+scale -> bf16 ----------
__global__ __launch_bounds__(256) void gatherB(const float* __restrict__ h,
                                               const float* __restrict__ sc,
                                               const int* __restrict__ nidx,
                                               unsigned short* __restrict__ out, int n) {
    int t = blockIdx.x * 256 + threadIdx.x;
    int i = t >> 5, q = t & 31;
    if (i >= n) return;
    int ni = nidx[i];
    if (ni < 0) return;
    float s = sc[i];
    float4 v = *(const float4*)(h + (size_t)i * F + q * 4);
    *(ushort4*)(out + (size_t)ni * F + q * 4) =
        make_ushort4(f2b(v.x * s), f2b(v.y * s), f2b(v.z * s), f2b(v.w * s));
}

// ---------- readout: 3-stage max/sum reduction (bf16 input) ----------
__global__ __launch_bounds__(128) void rpartK(const unsigned short* __restrict__ x, int k,
                                              float* __restrict__ pmax, float* __restrict__ psum) {
    int f = threadIdx.x;
    float m = -INFINITY, s = 0.f;
    for (int row = blockIdx.x; row < k; row += gridDim.x) {
        float v = b2f(x[(size_t)row * F + f]);
        m = fmaxf(m, v);
        s += v;
    }
    pmax[(size_t)blockIdx.x * F + f] = m;
    psum[(size_t)blockIdx.x * F + f] = s;
}

__global__ __launch_bounds__(128) void rmidK(const float* __restrict__ pmax,
                                             const float* __restrict__ psum,
                                             float* __restrict__ mmax,
                                             float* __restrict__ msum) {
    int f = threadIdx.x;
    int b0 = blockIdx.x * (RPB / RMID);
    float m = -INFINITY, s = 0.f;
#pragma unroll
    for (int i = 0; i < RPB / RMID; i++) {
        m = fmaxf(m, pmax[(size_t)(b0 + i) * F + f]);
        s += psum[(size_t)(b0 + i) * F + f];
    }
    mmax[(size_t)blockIdx.x * F + f] = m;
    msum[(size_t)blockIdx.x * F + f] = s;
}

__global__ __launch_bounds__(128) void rfinalK(const float* __restrict__ mmax,
                                               const float* __restrict__ msum, int k,
                                               float* __restrict__ r) {
    int f = threadIdx.x;
    float m = -INFINITY, s = 0.f;
    for (int b = 0; b < RMID; b++) {
        m = fmaxf(m, mmax[(size_t)b * F + f]);
        s += msum[(size_t)b * F + f];
    }
    r[f] += m;
    r[F + f] += s / (float)k;
}

// ---------- final MLP ----------
__global__ __launch_bounds__(256) void mlpK(const float* __restrict__ r,
                                            const float* __restrict__ W1, const float* __restrict__ b1,
                                            const float* __restrict__ W2, const float* __restrict__ b2,
                                            const float* __restrict__ W3, const float* __restrict__ b3,
                                            float* __restrict__ out) {
    __shared__ float z0[256], z1[128], z2[64];
    int t = threadIdx.x;
    z0[t] = r[t];
    __syncthreads();
    if (t < 128) {
        float a = b1[t];
        for (int kk = 0; kk < 256; kk++) a = fmaf(W1[t * 256 + kk], z0[kk], a);
        z1[t] = fmaxf(a, 0.f);
    }
    __syncthreads();
    if (t < 64) {
        float a = b2[t];
        for (int kk = 0; kk < 128; kk++) a = fmaf(W2[t * 128 + kk], z1[kk], a);
        z2[t] = fmaxf(a, 0.f);
    }
    __syncthreads();
    if (t < 2) {
        float a = b3[t];
        for (int kk = 0; kk < 64; kk++) a = fmaf(W3[t * 64 + kk], z2[kk], a);
        out[t] = a;
    }
}

extern "C" void kernel_launch(void* const* d_in, const int* in_sizes, int n_in,
                              void* d_out, int out_size, void* d_ws, size_t ws_size,
                              hipStream_t stream) {
    const float* x = (const float*)d_in[0];
    const int* ei = (const int*)d_in[1];
    const float* Wr[3]    = { (const float*)d_in[2],  (const float*)d_in[6],  (const float*)d_in[10] };
    const float* br[3]    = { (const float*)d_in[3],  (const float*)d_in[7],  (const float*)d_in[11] };
    const float* Wroot[3] = { (const float*)d_in[4],  (const float*)d_in[8],  (const float*)d_in[12] };
    const float* pw[3]    = { (const float*)d_in[5],  (const float*)d_in[9],  (const float*)d_in[13] };
    const float* W1 = (const float*)d_in[14];
    const float* b1 = (const float*)d_in[15];
    const float* W2 = (const float*)d_in[16];
    const float* b2 = (const float*)d_in[17];
    const float* W3 = (const float*)d_in[18];
    const float* b3 = (const float*)d_in[19];
    float* out = (float*)d_out;
    char* w = (char*)d_ws;

    size_t o = 0;
    auto alc = [&](size_t bytes) { size_t r = o; o += (bytes + 255) & ~(size_t)255; return r; };
    float*          bufA   = (float*)(w + alc((size_t)N0 * F * 4));
    unsigned short* xbf    = (unsigned short*)(w + alc((size_t)N0 * F * 2));
    unsigned short* aggbf  = (unsigned short*)(w + alc((size_t)N0 * F * 2));
    unsigned short* bufBbf = (unsigned short*)(w + alc((size_t)KP1 * F * 2));
    unsigned short* wbf    = (unsigned short*)(w + alc((size_t)6 * 16384 * 2));
    float*    sc     = (float*)(w + alc((size_t)N0 * 4));
    unsigned* keys   = (unsigned*)(w + alc((size_t)N0 * 4));
    int*      nidx   = (int*)(w + alc((size_t)N0 * 4));
    int*      sSrc0  = (int*)(w + alc((size_t)E0 * 4));
    int*      srcCA  = (int*)(w + alc((size_t)E0 * 4));
    int*      srcCB  = (int*)(w + alc((size_t)E0 * 4));
    unsigned* cnt    = (unsigned*)(w + alc((size_t)N0 * 4));
    unsigned* rowptr = (unsigned*)(w + alc((size_t)(N0 + 1) * 4));
    int*      origA  = (int*)(w + alc((size_t)N0 * 4));
    int*      origB  = (int*)(w + alc((size_t)N0 * 4));
    unsigned* chS    = (unsigned*)(w + alc(NCHUNK * 4));
    unsigned* chO    = (unsigned*)(w + alc(NCHUNK * 4));
    unsigned* hist   = (unsigned*)(w + alc(256 * 4));
    unsigned* st     = (unsigned*)(w + alc(64));
    int*      bGT    = (int*)(w + alc(128 * 4));
    int*      bEQ    = (int*)(w + alc(128 * 4));
    int*      sGT    = (int*)(w + alc(128 * 4));
    int*      sEQ    = (int*)(w + alc(128 * 4));
    float*    r      = (float*)(w + alc(256 * 4));
    float*    pmax   = (float*)(w + alc((size_t)RPB * F * 4));
    float*    psum   = (float*)(w + alc((size_t)RPB * F * 4));
    float*    mmax   = (float*)(w + alc((size_t)RMID * F * 4));
    float*    msum   = (float*)(w + alc((size_t)RMID * F * 4));
    if (o > ws_size) return;

    const int* srcOrig = ei;
    const int* dstOrig = ei + E0;

    // ----- one-time conversions -----
    cvt4K<<<(N0 * F / 4 + 255) / 256, 256, 0, stream>>>(x, xbf, N0 * F / 4);
    cvtWAllK<<<dim3(16, 6), 256, 0, stream>>>(Wr[0], Wroot[0], Wr[1], Wroot[1], Wr[2], Wroot[2], wbf);

    // ----- build dst-sorted CSR once (valid all layers: nidx is monotone) -----
    hipMemsetAsync(cnt, 0, (size_t)N0 * 4, stream);
    histDstK<<<(E0 + 255) / 256, 256, 0, stream>>>(dstOrig, cnt);
    scanReduceK<<<NCHUNK, 256, 0, stream>>>(cnt, chS, N0);
    scanChunksK<<<1, 1, 0, stream>>>(chS, chO, NCHUNK, rowptr + N0);
    scanFinalK<<<NCHUNK, 256, 0, stream>>>(cnt, chO, rowptr, N0);
    hipMemsetAsync(cnt, 0, (size_t)N0 * 4, stream);
    scatterFillK<<<(E0 + 255) / 256, 256, 0, stream>>>(srcOrig, dstOrig, rowptr, cnt, sSrc0);
    iotaK<<<(N0 + 255) / 256, 256, 0, stream>>>(origA, N0);

    hipMemsetAsync(r, 0, 256 * 4, stream);

    const int ns[3] = { N0, KP1, KP2 };
    const int ks[3] = { KP1, KP2, KP3 };
    const int* srcCur[3] = { sSrc0, srcCA, srcCB };
    int* srcNext[3] = { srcCA, srcCB, nullptr };
    const int* origCur[3] = { origA, origB, origA };
    int* origNext[3] = { origB, origA, nullptr };

    for (int L = 0; L < 3; L++) {
        int n = ns[L], k = ks[L];
        const unsigned short* xinbf = (L == 0) ? xbf : bufBbf;

        aggSegB<<<(n + 7) / 8, 256, 0, stream>>>(xinbf, srcCur[L], rowptr, origCur[L], aggbf, n);
        convM<<<(n + 127) / 128, 256, 0, stream>>>(aggbf, xinbf,
                                                   wbf + (size_t)(L * 2) * 16384,
                                                   wbf + (size_t)(L * 2 + 1) * 16384,
                                                   br[L], bufA, n);
        scoreK<<<(n + 3) / 4, 256, 0, stream>>>(bufA, pw[L], sc, keys, n);

        initSelK<<<1, 256, 0, stream>>>(hist, st, k);
        for (int p = 0; p < 4; p++) {
            histK<<<(n + 255) / 256, 256, 0, stream>>>(keys, n, p, st, hist);
            selectK<<<1, 256, 0, stream>>>(hist, st, p);
        }
        int nb = (n + 1023) / 1024;
        countsK<<<nb, 256, 0, stream>>>(keys, n, st, bGT, bEQ);
        scanK<<<1, 1, 0, stream>>>(bGT, bEQ, sGT, sEQ, nb);
        markK<<<nb, 256, 0, stream>>>(keys, n, st, sGT, sEQ, nidx);

        gatherB<<<(n * 32 + 255) / 256, 256, 0, stream>>>(bufA, sc, nidx, bufBbf, n);
        if (L < 2) {
            buildOrigK<<<(n + 255) / 256, 256, 0, stream>>>(origCur[L], nidx, origNext[L], n);
            remapSrcK<<<(E0 + 255) / 256, 256, 0, stream>>>(srcCur[L], nidx, srcNext[L]);
        }

        rpartK<<<RPB, 128, 0, stream>>>(bufBbf, k, pmax, psum);
        rmidK<<<RMID, 128, 0, stream>>>(pmax, psum, mmax, msum);
        rfinalK<<<1, 128, 0, stream>>>(mmax, msum, k, r);
    }

    mlpK<<<1, 256, 0, stream>>>(r, W1, b1, W2, b2, W3, b3, out);
}

// Round 7
// 640.144 us; speedup vs baseline: 4.8903x; 1.0444x over previous
//
#include <hip/hip_runtime.h>
#include <hip/hip_bf16.h>
#include <math.h>

#define N0 100000
#define E0 600000
#define KP1 80000
#define KP2 64000
#define KP3 51200
#define F 128
#define RPB 2048
#define RMID 128
#define SCAN_CHUNK 1024
#define NCHUNK ((N0 + SCAN_CHUNK - 1) / SCAN_CHUNK)

typedef __attribute__((ext_vector_type(8))) short short8;
typedef __attribute__((ext_vector_type(8))) unsigned short ushort8;
typedef __attribute__((ext_vector_type(4))) float f32x4;

// ---------- helpers ----------
__device__ __forceinline__ unsigned fkey(float f) {
    unsigned u = __float_as_uint(f);
    return u ^ ((u & 0x80000000u) ? 0xFFFFFFFFu : 0x80000000u);
}
__device__ __forceinline__ unsigned short f2b(float f) {
    __hip_bfloat16 h = __float2bfloat16(f);
    return *(unsigned short*)&h;
}
__device__ __forceinline__ float b2f(unsigned short u) {
    __hip_bfloat16 h;
    *(unsigned short*)&h = u;
    return __bfloat162float(h);
}

// ---------- conversions (once per launch) ----------
__global__ __launch_bounds__(256) void cvt4K(const float* __restrict__ in,
                                             unsigned short* __restrict__ out, int n4) {
    int i = blockIdx.x * 256 + threadIdx.x;
    if (i >= n4) return;
    float4 v = *(const float4*)(in + (size_t)i * 4);
    *(ushort4*)(out + (size_t)i * 4) = make_ushort4(f2b(v.x), f2b(v.y), f2b(v.z), f2b(v.w));
}

__global__ __launch_bounds__(256) void cvtWAllK(const float* __restrict__ a0, const float* __restrict__ a1,
                                                const float* __restrict__ a2, const float* __restrict__ a3,
                                                const float* __restrict__ a4, const float* __restrict__ a5,
                                                unsigned short* __restrict__ o) {
    int m = blockIdx.y;
    const float* src = (m == 0) ? a0 : (m == 1) ? a1 : (m == 2) ? a2 : (m == 3) ? a3 : (m == 4) ? a4 : a5;
    int i = blockIdx.x * 256 + threadIdx.x;
    float4 v = *(const float4*)(src + (size_t)i * 4);
    *(ushort4*)(o + (size_t)m * 16384 + (size_t)i * 4) = make_ushort4(f2b(v.x), f2b(v.y), f2b(v.z), f2b(v.w));
}

// normalized pooling weight: pwn = pw / ||pw||  (fp32, one block per layer)
__global__ __launch_bounds__(128) void pwnK(const float* __restrict__ p0, const float* __restrict__ p1,
                                            const float* __restrict__ p2, float* __restrict__ pwn) {
    __shared__ float sh[128];
    int l = blockIdx.x, t = threadIdx.x;
    const float* p = (l == 0) ? p0 : (l == 1) ? p1 : p2;
    float v = p[t];
    sh[t] = v * v;
    __syncthreads();
    for (int off = 64; off; off >>= 1) {
        if (t < off) sh[t] += sh[t + off];
        __syncthreads();
    }
    pwn[l * 128 + t] = v / sqrtf(sh[0]);
}

// ---------- CSR build (once per launch) ----------
__global__ __launch_bounds__(256) void histDstK(const int* __restrict__ dst, unsigned* __restrict__ cnt) {
    int e = blockIdx.x * 256 + threadIdx.x;
    if (e < E0) atomicAdd(&cnt[dst[e]], 1u);
}

__global__ __launch_bounds__(256) void scanReduceK(const unsigned* __restrict__ cnt,
                                                   unsigned* __restrict__ chunkSum, int nbins) {
    __shared__ unsigned sh[256];
    int base = blockIdx.x * SCAN_CHUNK + threadIdx.x * 4;
    unsigned s = 0;
#pragma unroll
    for (int i = 0; i < 4; i++) { int b = base + i; if (b < nbins) s += cnt[b]; }
    sh[threadIdx.x] = s;
    __syncthreads();
    for (int off = 128; off; off >>= 1) {
        if (threadIdx.x < off) sh[threadIdx.x] += sh[threadIdx.x + off];
        __syncthreads();
    }
    if (threadIdx.x == 0) chunkSum[blockIdx.x] = sh[0];
}

__global__ void scanChunksK(const unsigned* __restrict__ chunkSum, unsigned* __restrict__ chunkOff,
                            int nchunks, unsigned* __restrict__ totalOut) {
    if (threadIdx.x == 0) {
        unsigned run = 0;
        for (int i = 0; i < nchunks; i++) { chunkOff[i] = run; run += chunkSum[i]; }
        *totalOut = run;
    }
}

__global__ __launch_bounds__(256) void scanFinalK(const unsigned* __restrict__ cnt,
                                                  const unsigned* __restrict__ chunkOff,
                                                  unsigned* __restrict__ rowptr, int nbins) {
    __shared__ unsigned sh[256];
    int t = threadIdx.x;
    int base = blockIdx.x * SCAN_CHUNK + t * 4;
    unsigned c[4], s = 0;
#pragma unroll
    for (int i = 0; i < 4; i++) { int b = base + i; c[i] = (b < nbins) ? cnt[b] : 0u; s += c[i]; }
    sh[t] = s;
    __syncthreads();
    for (int off = 1; off < 256; off <<= 1) {
        unsigned v = (t >= off) ? sh[t - off] : 0u;
        __syncthreads();
        sh[t] += v;
        __syncthreads();
    }
    unsigned basep = chunkOff[blockIdx.x] + sh[t] - s;
#pragma unroll
    for (int i = 0; i < 4; i++) {
        int b = base + i;
        if (b < nbins) { rowptr[b] = basep; basep += c[i]; }
    }
}

__global__ __launch_bounds__(256) void scatterFillK(const int* __restrict__ src,
                                                    const int* __restrict__ dst,
                                                    const unsigned* __restrict__ rowptr,
                                                    unsigned* __restrict__ fill,
                                                    int* __restrict__ sortedSrc) {
    int e = blockIdx.x * 256 + threadIdx.x;
    if (e >= E0) return;
    int d = dst[e];
    unsigned p = rowptr[d] + atomicAdd(&fill[d], 1u);
    sortedSrc[p] = src[e];
}

__global__ __launch_bounds__(256) void iotaK(int* o, int n) {
    int i = blockIdx.x * 256 + threadIdx.x;
    if (i < n) o[i] = i;
}

// ---------- segmented aggregation: 16-lane groups, 4-edge unroll ----------
__global__ __launch_bounds__(256) void aggSegB(const unsigned short* __restrict__ x,
                                               const int* __restrict__ srcCur,
                                               const unsigned* __restrict__ rowptr,
                                               const int* __restrict__ orig,
                                               unsigned short* __restrict__ agg, int n) {
    int g = blockIdx.x * 16 + (threadIdx.x >> 4);
    int q = threadIdx.x & 15;
    if (g >= n) return;
    int d = orig[g];
    unsigned e0 = rowptr[d], e1 = rowptr[d + 1];
    float a[8];
#pragma unroll
    for (int j = 0; j < 8; j++) a[j] = 0.f;
    unsigned e = e0;
    for (; e + 4 <= e1; e += 4) {
        int s0 = srcCur[e], s1 = srcCur[e + 1], s2 = srcCur[e + 2], s3 = srcCur[e + 3];
        ushort8 v0 = *(const ushort8*)(x + (size_t)(s0 < 0 ? 0 : s0) * F + q * 8);
        ushort8 v1 = *(const ushort8*)(x + (size_t)(s1 < 0 ? 0 : s1) * F + q * 8);
        ushort8 v2 = *(const ushort8*)(x + (size_t)(s2 < 0 ? 0 : s2) * F + q * 8);
        ushort8 v3 = *(const ushort8*)(x + (size_t)(s3 < 0 ? 0 : s3) * F + q * 8);
        float m0 = s0 < 0 ? 0.f : 1.f, m1 = s1 < 0 ? 0.f : 1.f;
        float m2 = s2 < 0 ? 0.f : 1.f, m3 = s3 < 0 ? 0.f : 1.f;
#pragma unroll
        for (int j = 0; j < 8; j++) {
            a[j] = fmaf(b2f(v0[j]), m0, a[j]);
            a[j] = fmaf(b2f(v1[j]), m1, a[j]);
            a[j] = fmaf(b2f(v2[j]), m2, a[j]);
            a[j] = fmaf(b2f(v3[j]), m3, a[j]);
        }
    }
    for (; e < e1; e++) {
        int s = srcCur[e];
        if (s < 0) continue;
        ushort8 v = *(const ushort8*)(x + (size_t)s * F + q * 8);
#pragma unroll
        for (int j = 0; j < 8; j++) a[j] += b2f(v[j]);
    }
    ushort8 o;
#pragma unroll
    for (int j = 0; j < 8; j++) o[j] = f2b(a[j]);
    *(ushort8*)(agg + (size_t)g * F + q * 8) = o;
}

__global__ __launch_bounds__(256) void buildOrigK(const int* __restrict__ origIn,
                                                  const int* __restrict__ nidx,
                                                  int* __restrict__ origOut, int n) {
    int i = blockIdx.x * 256 + threadIdx.x;
    if (i < n) { int ni = nidx[i]; if (ni >= 0) origOut[ni] = origIn[i]; }
}

__global__ __launch_bounds__(256) void remapSrcK(const int* __restrict__ srcIn,
                                                 const int* __restrict__ nidx,
                                                 int* __restrict__ srcOut) {
    int e = blockIdx.x * 256 + threadIdx.x;
    if (e >= E0) return;
    int s = srcIn[e];
    srcOut[e] = (s >= 0) ? nidx[s] : -1;
}

// ---------- MFMA conv + fused score epilogue: hbf = relu(...), sc/keys per row ----------
#define CPAD 40
__global__ __launch_bounds__(256) void convM(const unsigned short* __restrict__ A0,
                                             const unsigned short* __restrict__ A1,
                                             const unsigned short* __restrict__ W0,
                                             const unsigned short* __restrict__ W1,
                                             const float* __restrict__ br,
                                             const float* __restrict__ pwn,
                                             unsigned short* __restrict__ hbf,
                                             float* __restrict__ sc,
                                             unsigned* __restrict__ keys, int n) {
    __shared__ unsigned short As[128 * CPAD];
    __shared__ unsigned short Bs[128 * CPAD];
    int tid = threadIdx.x;
    int w = tid >> 6, l = tid & 63;
    int r = l & 15, g = l >> 4;
    int bm = blockIdx.x * 128;
    int srow = tid >> 2, q4 = tid & 3;

    f32x4 acc[2][8];
#pragma unroll
    for (int m = 0; m < 2; m++)
#pragma unroll
        for (int c = 0; c < 8; c++) acc[m][c] = (f32x4){0.f, 0.f, 0.f, 0.f};

    for (int ph = 0; ph < 2; ph++) {
        const unsigned short* A = ph ? A1 : A0;
        const unsigned short* W = ph ? W1 : W0;
        for (int kk = 0; kk < 128; kk += 32) {
            __syncthreads();
#pragma unroll
            for (int h2 = 0; h2 < 2; h2++) {
                int rr = srow + h2 * 64;
                uint4 av = make_uint4(0u, 0u, 0u, 0u);
                if (bm + rr < n) av = *(const uint4*)(A + (size_t)(bm + rr) * F + kk + q4 * 8);
                *(uint4*)(&As[rr * CPAD + q4 * 8]) = av;
                uint4 wv = *(const uint4*)(W + (size_t)rr * F + kk + q4 * 8);
                *(uint4*)(&Bs[rr * CPAD + q4 * 8]) = wv;
            }
            __syncthreads();
            short8 af[2], bf[8];
#pragma unroll
            for (int m = 0; m < 2; m++)
                af[m] = *(const short8*)(&As[(w * 32 + m * 16 + r) * CPAD + g * 8]);
#pragma unroll
            for (int c = 0; c < 8; c++)
                bf[c] = *(const short8*)(&Bs[(c * 16 + r) * CPAD + g * 8]);
#pragma unroll
            for (int m = 0; m < 2; m++)
#pragma unroll
                for (int c = 0; c < 8; c++)
                    acc[m][c] = __builtin_amdgcn_mfma_f32_16x16x32_bf16(af[m], bf[c], acc[m][c], 0, 0, 0);
        }
    }

    float pd[2][4];
#pragma unroll
    for (int m = 0; m < 2; m++)
#pragma unroll
        for (int j = 0; j < 4; j++) pd[m][j] = 0.f;

#pragma unroll
    for (int c = 0; c < 8; c++) {
        int col = c * 16 + r;
        float bias = br[col];
        float pwc = pwn[col];
#pragma unroll
        for (int m = 0; m < 2; m++) {
#pragma unroll
            for (int j = 0; j < 4; j++) {
                int row = bm + w * 32 + m * 16 + g * 4 + j;
                float h = fmaxf(acc[m][c][j] + bias, 0.f);
                pd[m][j] += h * pwc;
                if (row < n) hbf[(size_t)row * F + col] = f2b(h);
            }
        }
    }
#pragma unroll
    for (int m = 0; m < 2; m++) {
#pragma unroll
        for (int j = 0; j < 4; j++) {
            float p = pd[m][j];
            p += __shfl_xor(p, 1);
            p += __shfl_xor(p, 2);
            p += __shfl_xor(p, 4);
            p += __shfl_xor(p, 8);
            if (r == 0) {
                int row = bm + w * 32 + m * 16 + g * 4 + j;
                if (row < n) {
                    float s = tanhf(p);
                    sc[row] = s;
                    keys[row] = fkey(s);
                }
            }
        }
    }
}

// ---------- radix select: init ----------
__global__ void initSelK(unsigned* hist, unsigned* st, unsigned* done, unsigned* done2, int k) {
    hist[threadIdx.x] = 0;
    if (threadIdx.x == 0) { st[0] = 0u; st[1] = (unsigned)k; *done = 0u; *done2 = 0u; }
}

// ---------- fused histogram + select (last-block-done) ----------
__global__ __launch_bounds__(256) void histSelK(const unsigned* __restrict__ keys, int n,
                                                int p, unsigned* __restrict__ st,
                                                unsigned* __restrict__ hist,
                                                unsigned* __restrict__ done, int nb) {
    __shared__ unsigned lh[256];
    __shared__ bool last;
    int tid = threadIdx.x;
    lh[tid] = 0;
    __syncthreads();
    unsigned prefix = st[0];
    int i = blockIdx.x * 256 + tid;
    if (i < n) {
        unsigned key = keys[i];
        bool m = (p == 0) || ((key >> (32 - 8 * p)) == (prefix >> (32 - 8 * p)));
        if (m) atomicAdd(&lh[(key >> (24 - 8 * p)) & 255u], 1u);
    }
    __syncthreads();
    if (lh[tid]) atomicAdd(&hist[tid], lh[tid]);
    __syncthreads();                       // drains the hist atomics (vmcnt) for whole block
    if (tid == 0) {
        __threadfence();
        last = (atomicAdd(done, 1u) == (unsigned)(nb - 1));
    }
    __syncthreads();
    if (!last) return;
    lh[tid] = atomicAdd(&hist[tid], 0u);   // device-scope read: all blocks' adds visible
    __syncthreads();
    hist[tid] = 0;                         // reset for next pass (read next dispatch)
    if (tid == 0) {
        unsigned krem = st[1], cum = 0;
        for (int b = 255; b >= 0; b--) {
            unsigned c = lh[b];
            if (cum + c >= krem) {
                st[0] |= ((unsigned)b) << (24 - 8 * p);
                st[1] = krem - cum;
                break;
            }
            cum += c;
        }
        *done = 0u;
    }
}

// ---------- counts + fused scan (last-block-done) ----------
__global__ __launch_bounds__(256) void countsK(const unsigned* __restrict__ keys, int n,
                                               const unsigned* __restrict__ st,
                                               int* __restrict__ bGT, int* __restrict__ bEQ,
                                               int* __restrict__ sGT, int* __restrict__ sEQ,
                                               unsigned* __restrict__ done2, int nb) {
    __shared__ int cg_, ce_;
    __shared__ bool last;
    int tid = threadIdx.x;
    if (tid == 0) { cg_ = 0; ce_ = 0; }
    __syncthreads();
    unsigned t = st[0];
    int g = 0, e = 0;
    for (int it = 0; it < 4; it++) {
        int i = blockIdx.x * 1024 + it * 256 + tid;
        if (i < n) {
            unsigned k = keys[i];
            g += (k > t);
            e += (k == t);
        }
    }
    atomicAdd(&cg_, g);
    atomicAdd(&ce_, e);
    __syncthreads();
    if (tid == 0) {
        bGT[blockIdx.x] = cg_;
        bEQ[blockIdx.x] = ce_;
        __threadfence();
        last = (atomicAdd(done2, 1u) == (unsigned)(nb - 1));
    }
    __syncthreads();
    if (!last) return;
    if (tid == 0) {
        int gs = 0, es = 0;
        for (int b = 0; b < nb; b++) {
            sGT[b] = gs; sEQ[b] = es;
            gs += atomicAdd(&bGT[b], 0);
            es += atomicAdd(&bEQ[b], 0);
        }
        *done2 = 0u;
    }
}

__global__ __launch_bounds__(256) void markK(const unsigned* __restrict__ keys, int n,
                                             const unsigned* __restrict__ st,
                                             const int* __restrict__ sGT,
                                             const int* __restrict__ sEQ,
                                             int* __restrict__ nidx) {
    __shared__ int wG[4], wE[4];
    __shared__ int runG, runE;
    int tid = threadIdx.x, wv = tid >> 6, lane = tid & 63;
    if (tid == 0) { runG = 0; runE = 0; }
    unsigned t = st[0];
    int needEq = (int)st[1];
    int gOff = sGT[blockIdx.x], eOff = sEQ[blockIdx.x];
    unsigned long long mlt = (((unsigned long long)1) << lane) - 1ull;
    __syncthreads();
    for (int it = 0; it < 4; it++) {
        int i = blockIdx.x * 1024 + it * 256 + tid;
        bool inb = i < n;
        unsigned k = inb ? keys[i] : 0u;
        bool pG = inb && (k > t), pE = inb && (k == t);
        unsigned long long bG = __ballot(pG), bE = __ballot(pE);
        int lpG = __popcll(bG & mlt), lpE = __popcll(bE & mlt);
        if (lane == 0) { wG[wv] = __popcll(bG); wE[wv] = __popcll(bE); }
        __syncthreads();
        int woG = 0, woE = 0;
        for (int w = 0; w < wv; w++) { woG += wG[w]; woE += wE[w]; }
        int gB = gOff + runG + woG + lpG;
        int eB = eOff + runE + woE + lpE;
        int ni = -1;
        if (pG) ni = gB + (eB < needEq ? eB : needEq);
        else if (pE && eB < needEq) ni = gB + eB;
        if (inb) nidx[i] = ni;
        __syncthreads();
        if (tid == 0) {
            runG += wG[0] + wG[1] + wG[2] + wG[3];
            runE += wE[0] + wE[1] + wE[2] + wE[3];
        }
        __syncthreads();
    }
}

// ---------- gather+scale (bf16 in, bf16 out) ----------
__global__ __launch_bounds__(256) void gatherB(const unsigned short* __restrict__ h,
                                               const float* __restrict__ sc,
                                               const int* __restrict__ nidx,
                                               unsigned short* __restrict__ out, int n) {
    int t = blockIdx.x * 256 + threadIdx.x;
    int i = t >> 4, q = t & 15;
    if (i >= n) return;
    int ni = nidx[i];
    if (ni < 0) return;
    float s = sc[i];
    ushort8 v = *(const ushort8*)(h + (size_t)i * F + q * 8);
    ushort8 o;
#pragma unroll
    for (int j = 0; j < 8; j++) o[j] = f2b(b2f(v[j]) * s);
    *(ushort8*)(out + (size_t)ni * F + q * 8) = o;
}

// ---------- readout: 3-stage max/sum reduction (bf16 input) ----------
__global__ __launch_bounds__(128) void rpartK(const unsigned short* __restrict__ x, int k,
                                              float* __restrict__ pmax, float* __restrict__ psum) {
    int f = threadIdx.x;
    float m = -INFINITY, s = 0.f;
    for (int row = blockIdx.x; row < k; row += gridDim.x) {
        float v = b2f(x[(size_t)row * F + f]);
        m = fmaxf(m, v);
        s += v;
    }
    pmax[(size_t)blockIdx.x * F + f] = m;
    psum[(size_t)blockIdx.x * F + f] = s;
}

__global__ __launch_bounds__(128) void rmidK(const float* __restrict__ pmax,
                                             const float* __restrict__ psum,
                                             float* __restrict__ mmax,
                                             float* __restrict__ msum) {
    int f = threadIdx.x;
    int b0 = blockIdx.x * (RPB / RMID);
    float m = -INFINITY, s = 0.f;
#pragma unroll
    for (int i = 0; i < RPB / RMID; i++) {
        m = fmaxf(m, pmax[(size_t)(b0 + i) * F + f]);
        s += psum[(size_t)(b0 + i) * F + f];
    }
    mmax[(size_t)blockIdx.x * F + f] = m;
    msum[(size_t)blockIdx.x * F + f] = s;
}

__global__ __launch_bounds__(128) void rfinalK(const float* __restrict__ mmax,
                                               const float* __restrict__ msum, int k,
                                               float* __restrict__ r) {
    int f = threadIdx.x;
    float m = -INFINITY, s = 0.f;
    for (int b = 0; b < RMID; b++) {
        m = fmaxf(m, mmax[(size_t)b * F + f]);
        s += msum[(size_t)b * F + f];
    }
    r[f] += m;
    r[F + f] += s / (float)k;
}

// ---------- final MLP ----------
__global__ __launch_bounds__(256) void mlpK(const float* __restrict__ r,
                                            const float* __restrict__ W1, const float* __restrict__ b1,
                                            const float* __restrict__ W2, const float* __restrict__ b2,
                                            const float* __restrict__ W3, const float* __restrict__ b3,
                                            float* __restrict__ out) {
    __shared__ float z0[256], z1[128], z2[64];
    int t = threadIdx.x;
    z0[t] = r[t];
    __syncthreads();
    if (t < 128) {
        float a = b1[t];
        for (int kk = 0; kk < 256; kk++) a = fmaf(W1[t * 256 + kk], z0[kk], a);
        z1[t] = fmaxf(a, 0.f);
    }
    __syncthreads();
    if (t < 64) {
        float a = b2[t];
        for (int kk = 0; kk < 128; kk++) a = fmaf(W2[t * 128 + kk], z1[kk], a);
        z2[t] = fmaxf(a, 0.f);
    }
    __syncthreads();
    if (t < 2) {
        float a = b3[t];
        for (int kk = 0; kk < 64; kk++) a = fmaf(W3[t * 64 + kk], z2[kk], a);
        out[t] = a;
    }
}

extern "C" void kernel_launch(void* const* d_in, const int* in_sizes, int n_in,
                              void* d_out, int out_size, void* d_ws, size_t ws_size,
                              hipStream_t stream) {
    const float* x = (const float*)d_in[0];
    const int* ei = (const int*)d_in[1];
    const float* Wr[3]    = { (const float*)d_in[2],  (const float*)d_in[6],  (const float*)d_in[10] };
    const float* br[3]    = { (const float*)d_in[3],  (const float*)d_in[7],  (const float*)d_in[11] };
    const float* Wroot[3] = { (const float*)d_in[4],  (const float*)d_in[8],  (const float*)d_in[12] };
    const float* pw[3]    = { (const float*)d_in[5],  (const float*)d_in[9],  (const float*)d_in[13] };
    const float* W1 = (const float*)d_in[14];
    const float* b1 = (const float*)d_in[15];
    const float* W2 = (const float*)d_in[16];
    const float* b2 = (const float*)d_in[17];
    const float* W3 = (const float*)d_in[18];
    const float* b3 = (const float*)d_in[19];
    float* out = (float*)d_out;
    char* w = (char*)d_ws;

    size_t o = 0;
    auto alc = [&](size_t bytes) { size_t r = o; o += (bytes + 255) & ~(size_t)255; return r; };
    unsigned short* hbf    = (unsigned short*)(w + alc((size_t)N0 * F * 2));
    unsigned short* xbf    = (unsigned short*)(w + alc((size_t)N0 * F * 2));
    unsigned short* aggbf  = (unsigned short*)(w + alc((size_t)N0 * F * 2));
    unsigned short* bufBbf = (unsigned short*)(w + alc((size_t)KP1 * F * 2));
    unsigned short* wbf    = (unsigned short*)(w + alc((size_t)6 * 16384 * 2));
    float*    pwn    = (float*)(w + alc(3 * 128 * 4));
    float*    sc     = (float*)(w + alc((size_t)N0 * 4));
    unsigned* keys   = (unsigned*)(w + alc((size_t)N0 * 4));
    int*      nidx   = (int*)(w + alc((size_t)N0 * 4));
    int*      sSrc0  = (int*)(w + alc((size_t)E0 * 4));
    int*      srcCA  = (int*)(w + alc((size_t)E0 * 4));
    int*      srcCB  = (int*)(w + alc((size_t)E0 * 4));
    unsigned* cnt    = (unsigned*)(w + alc((size_t)N0 * 4));
    unsigned* rowptr = (unsigned*)(w + alc((size_t)(N0 + 1) * 4));
    int*      origA  = (int*)(w + alc((size_t)N0 * 4));
    int*      origB  = (int*)(w + alc((size_t)N0 * 4));
    unsigned* chS    = (unsigned*)(w + alc(NCHUNK * 4));
    unsigned* chO    = (unsigned*)(w + alc(NCHUNK * 4));
    unsigned* hist   = (unsigned*)(w + alc(256 * 4));
    unsigned* st     = (unsigned*)(w + alc(64));
    unsigned* done   = (unsigned*)(w + alc(64));
    unsigned* done2  = (unsigned*)(w + alc(64));
    int*      bGT    = (int*)(w + alc(128 * 4));
    int*      bEQ    = (int*)(w + alc(128 * 4));
    int*      sGT    = (int*)(w + alc(128 * 4));
    int*      sEQ    = (int*)(w + alc(128 * 4));
    float*    r      = (float*)(w + alc(256 * 4));
    float*    pmax   = (float*)(w + alc((size_t)RPB * F * 4));
    float*    psum   = (float*)(w + alc((size_t)RPB * F * 4));
    float*    mmax   = (float*)(w + alc((size_t)RMID * F * 4));
    float*    msum   = (float*)(w + alc((size_t)RMID * F * 4));
    if (o > ws_size) return;

    const int* srcOrig = ei;
    const int* dstOrig = ei + E0;

    // ----- one-time conversions -----
    cvt4K<<<(N0 * F / 4 + 255) / 256, 256, 0, stream>>>(x, xbf, N0 * F / 4);
    cvtWAllK<<<dim3(16, 6), 256, 0, stream>>>(Wr[0], Wroot[0], Wr[1], Wroot[1], Wr[2], Wroot[2], wbf);
    pwnK<<<3, 128, 0, stream>>>(pw[0], pw[1], pw[2], pwn);

    // ----- build dst-sorted CSR once (valid all layers: nidx is monotone) -----
    hipMemsetAsync(cnt, 0, (size_t)N0 * 4, stream);
    histDstK<<<(E0 + 255) / 256, 256, 0, stream>>>(dstOrig, cnt);
    scanReduceK<<<NCHUNK, 256, 0, stream>>>(cnt, chS, N0);
    scanChunksK<<<1, 1, 0, stream>>>(chS, chO, NCHUNK, rowptr + N0);
    scanFinalK<<<NCHUNK, 256, 0, stream>>>(cnt, chO, rowptr, N0);
    hipMemsetAsync(cnt, 0, (size_t)N0 * 4, stream);
    scatterFillK<<<(E0 + 255) / 256, 256, 0, stream>>>(srcOrig, dstOrig, rowptr, cnt, sSrc0);
    iotaK<<<(N0 + 255) / 256, 256, 0, stream>>>(origA, N0);

    hipMemsetAsync(r, 0, 256 * 4, stream);

    const int ns[3] = { N0, KP1, KP2 };
    const int ks[3] = { KP1, KP2, KP3 };
    const int* srcCur[3] = { sSrc0, srcCA, srcCB };
    int* srcNext[3] = { srcCA, srcCB, nullptr };
    const int* origCur[3] = { origA, origB, origA };
    int* origNext[3] = { origB, origA, nullptr };

    for (int L = 0; L < 3; L++) {
        int n = ns[L], k = ks[L];
        const unsigned short* xinbf = (L == 0) ? xbf : bufBbf;

        aggSegB<<<(n + 15) / 16, 256, 0, stream>>>(xinbf, srcCur[L], rowptr, origCur[L], aggbf, n);
        convM<<<(n + 127) / 128, 256, 0, stream>>>(aggbf, xinbf,
                                                   wbf + (size_t)(L * 2) * 16384,
                                                   wbf + (size_t)(L * 2 + 1) * 16384,
                                                   br[L], pwn + L * 128, hbf, sc, keys, n);

        initSelK<<<1, 256, 0, stream>>>(hist, st, done, done2, k);
        int nbh = (n + 255) / 256;
        for (int p = 0; p < 4; p++)
            histSelK<<<nbh, 256, 0, stream>>>(keys, n, p, st, hist, done, nbh);
        int nb = (n + 1023) / 1024;
        countsK<<<nb, 256, 0, stream>>>(keys, n, st, bGT, bEQ, sGT, sEQ, done2, nb);
        markK<<<nb, 256, 0, stream>>>(keys, n, st, sGT, sEQ, nidx);

        gatherB<<<(n * 16 + 255) / 256, 256, 0, stream>>>(hbf, sc, nidx, bufBbf, n);
        if (L < 2) {
            buildOrigK<<<(n + 255) / 256, 256, 0, stream>>>(origCur[L], nidx, origNext[L], n);
            remapSrcK<<<(E0 + 255) / 256, 256, 0, stream>>>(srcCur[L], nidx, srcNext[L]);
        }

        rpartK<<<RPB, 128, 0, stream>>>(bufBbf, k, pmax, psum);
        rmidK<<<RMID, 128, 0, stream>>>(pmax, psum, mmax, msum);
        rfinalK<<<1, 128, 0, stream>>>(mmax, msum, k, r);
    }

    mlpK<<<1, 256, 0, stream>>>(r, W1, b1, W2, b2, W3, b3, out);
}